// Round 1
// baseline (681.100 us; speedup 1.0000x reference)
//
#include <hip/hip_runtime.h>

// ScoreNetGNN: B=50000 graphs x 7 nodes, fully-connected (42 edges/graph).
// R6: MFMA pipeline (16x16x32 bf16 split hi+lo). R7: strides/LDS. R8: two
// graphs/wave. R9: 128-thr blocks. R11: two-chain accum + pipelined edgeconv.
// R12: truncation-split, resident edge B-frags. R13: parallel pack + packed-H.
// R14 (this): occupancy push. LDS/wave 15744 -> 8832:
//  (1) XS2 eliminated: xs A-frags (constant per lane for whole kernel) staged
//      once through W during the embedding phase, then kept in registers.
//  (2) H1 eliminated: edge-H staging single-buffered in W (chunk-c frags are
//      in regs before chunk c+1 is staged; same-wave DS is in-order).
// Block LDS 31744 -> 17920 B: 5 -> 8 resident blocks/CU (VGPR-capped at 16
// waves/CU). __launch_bounds__(128,4) pins VGPR <= 128 to hold the cap.
// f32 I/O hardcoded (R3 counters: WRITE_SIZE = 4 B/elem).

#define NB 50000

typedef unsigned short u16;
typedef unsigned int u32;
typedef short short8 __attribute__((ext_vector_type(8)));
typedef float f32x4 __attribute__((ext_vector_type(4)));

// d_ws fragment offsets (u16 units). frag stride 1024 u16 (hi 512 | lo 512),
// lane entry = 8 u16 (16B). Total 94208 u16 = 188416 bytes.
#define OFF_I  0
#define OFF_1A 8192
#define OFF_2A 24576
#define OFF_3A 49152
#define OFF_1B 73728
#define OFF_2B 81920
#define OFF_WT 90112
#define OFF_3B 92160

// LDS per-wave geometry (bytes). W dual-use region (4608B):
//  - as X: 16 rows x 64 bf16 @ stride 144, hi [0,2304) lo [2304,4608)
//  - as H: 16 rows x 64 packed u32 @ stride 272 (68 dw -> <=2-way, free)
//  - transiently as E/xs staging (cols 0-31) during the embedding phase
// Sb: f32 C @ stride 264.
#define HSTR 144
#define HLO  2304
#define H2S  272
#define SSTR 264
#define WREG 8832    // W 4608 + Sb 4224

__device__ __forceinline__ float b2f(u16 u) {
    return __uint_as_float(((u32)u) << 16);
}
__device__ __forceinline__ u16 f2b(float f) {
    u32 u = __float_as_uint(f);
    u += 0x7FFFu + ((u >> 16) & 1u);   // RNE
    return (u16)(u >> 16);
}
// split v into bf16 hi (truncated, v-hi exact) + bf16 lo (RNE of residual)
__device__ __forceinline__ void split2(float v, u16& h, u16& l) {
    u32 u = __float_as_uint(v);
    h = (u16)(u >> 16);
    float d = v - __uint_as_float(u & 0xffff0000u);
    l = f2b(d);
}
// packed u32: low16 = hi(trunc), high16 = lo(RNE)
__device__ __forceinline__ u32 splitpack(float v) {
    u32 u = __float_as_uint(v);
    float d = v - __uint_as_float(u & 0xffff0000u);
    u32 r = __float_as_uint(d);
    r += 0x7FFFu + ((r >> 16) & 1u);
    return __builtin_amdgcn_perm(r, u, 0x07060302);  // [u.b2,u.b3,r.b2,r.b3]
}
__device__ __forceinline__ float bcast(float v, int l) {
    return __uint_as_float(__builtin_amdgcn_readlane(__float_as_uint(v), l));
}

// ---- setup: pack weights into split-bf16 MFMA B-fragments ----
// grid (92, 8): blockIdx.y = element j within lane entry; 128 thr = half x lane.
__global__ __launch_bounds__(128) void pack_kernel(
    const float* __restrict__ wi2, const float* __restrict__ w1a,
    const float* __restrict__ w2a, const float* __restrict__ w3a,
    const float* __restrict__ w1b, const float* __restrict__ w2b,
    const float* __restrict__ wt,  const float* __restrict__ w3b,
    u16* __restrict__ ws)
{
    int blk = blockIdx.x;
    int j    = blockIdx.y;
    int half = threadIdx.x >> 6;          // 0 = hi, 1 = lo
    int lane = threadIdx.x & 63;
    float v;
    u16* dst;
    if (blk < 88) {
        const float* src; int NT, qoff, obase, frag;
        if (blk < 8)       { src = wi2; NT = 4; qoff = 0;  obase = OFF_I;  frag = blk;      }
        else if (blk < 24) { src = w1a; NT = 8; qoff = 64; obase = OFF_1A; frag = blk - 8;  }
        else if (blk < 48) { src = w2a; NT = 8; qoff = 96; obase = OFF_2A; frag = blk - 24; }
        else if (blk < 72) { src = w3a; NT = 8; qoff = 96; obase = OFF_3A; frag = blk - 48; }
        else if (blk < 80) { src = w1b; NT = 4; qoff = 0;  obase = OFF_1B; frag = blk - 72; }
        else               { src = w2b; NT = 4; qoff = 0;  obase = OFF_2B; frag = blk - 80; }
        int kt = frag / NT, nt = frag % NT;
        int k = kt * 32 + (lane >> 4) * 8 + j;
        int n = nt * 16 + (lane & 15);
        int idx = (n < 64) ? (k * 64 + n) : ((qoff + k) * 64 + (n - 64));
        v = src[idx];
        dst = ws + obase + frag * 1024 + half * 512 + lane * 8 + j;
    } else if (blk < 90) {               // wt (32,32): 2 n-frags
        int frag = blk - 88;
        int k = (lane >> 4) * 8 + j;
        int n = frag * 16 + (lane & 15);
        v = wt[k * 32 + n];
        dst = ws + OFF_WT + frag * 1024 + half * 512 + lane * 8 + j;
    } else {                             // w3b (64,3): 2 k-frags, cols 3..15 = 0
        int frag = blk - 90;
        int k = frag * 32 + (lane >> 4) * 8 + j;
        int n = lane & 15;
        v = (n < 3) ? w3b[k * 3 + n] : 0.f;
        dst = ws + OFF_3B + frag * 1024 + half * 512 + lane * 8 + j;
    }
    u16 hi = f2b(v);
    *dst = (half == 0) ? hi : f2b(v - b2f(hi));
}

__device__ __forceinline__ f32x4 mfma1(short8 a, short8 b, f32x4 acc) {
    return __builtin_amdgcn_mfma_f32_16x16x32_bf16(a, b, acc, 0, 0, 0);
}
__device__ __forceinline__ f32x4 mfma3(short8 ah, short8 al, short8 bh, short8 bl, f32x4 acc) {
    acc = mfma1(ah, bh, acc);
    acc = mfma1(ah, bl, acc);
    acc = mfma1(al, bh, acc);
    return acc;   // lo*lo dropped
}

// node k (0..13) -> row (g0 rows 0-6, g1 rows 8-14; rows 7,15 stale/unread)
#define ROW(k) ((k) < 7 ? (k) : (k) + 1)

// write 14 node values (64 cols) into region G as X (bf16 hi/lo planes)
__device__ __forceinline__ void writeX64_14(char* G, int L, const float* v) {
#pragma unroll
    for (int k = 0; k < 14; ++k) {
        int r = ROW(k);
        u16 h, l;
        split2(v[k], h, l);
        *(u16*)(G + r * HSTR + L * 2) = h;
        *(u16*)(G + HLO + r * HSTR + L * 2) = l;
    }
}
// A-frags kt 0,1 from G (cols 0-63); kt 2 (xs, cols 64-95) is register-resident.
__device__ __forceinline__ void loadA2(const char* G, int L, short8* Ah, short8* Al) {
#pragma unroll
    for (int kt = 0; kt < 2; ++kt) {
        Ah[kt] = *(const short8*)(G + (L & 15) * HSTR + kt * 64 + (L >> 4) * 16);
        Al[kt] = *(const short8*)(G + HLO + (L & 15) * HSTR + kt * 64 + (L >> 4) * 16);
    }
}
// One 4-N-tile GEMM pass: S[row][col 0..63] = A(16xK) @ B(Kx64).
template<int KT, int NT>
__device__ __forceinline__ void lin_pass(const u16* __restrict__ ws, int off, int nt0,
                                         const short8* Ah, const short8* Al,
                                         char* Sg, int L) {
#pragma unroll
    for (int ntc = 0; ntc < 4; ++ntc) {
        f32x4 a1 = {0.f, 0.f, 0.f, 0.f}, a2 = {0.f, 0.f, 0.f, 0.f};
#pragma unroll
        for (int kt = 0; kt < KT; ++kt) {
            int f = kt * NT + nt0 + ntc;
            short8 bh = *(const short8*)(ws + off + f * 1024 + L * 8);
            short8 bl = *(const short8*)(ws + off + f * 1024 + 512 + L * 8);
            a1 = mfma1(Ah[kt], bh, a1);
            a2 = mfma1(Ah[kt], bl, a2);
            a2 = mfma1(Al[kt], bh, a2);
        }
#pragma unroll
        for (int rr = 0; rr < 4; ++rr)   // C: row=(L>>4)*4+rr, col=ntc*16+(L&15)
            *(float*)(Sg + ((L >> 4) * 4 + rr) * SSTR + ntc * 64 + (L & 15) * 4) = a1[rr] + a2[rr];
    }
}
__device__ __forceinline__ void readS14(const char* Sg, int L, float* o) {
#pragma unroll
    for (int k = 0; k < 14; ++k) o[k] = *(const float*)(Sg + ROW(k) * SSTR + L * 4);
}
// stage 16 edge rows (chunk c of 6; 84 real edges) as PACKED u32 per element
__device__ __forceinline__ void stageH2(char* G, int c, const float* pp, const float* qq, int L) {
#pragma unroll
    for (int r = 0; r < 16; ++r) {
        int e = c * 16 + r;
        if (e < 84) {
            int gb = (e >= 42) ? 1 : 0;
            int el = e - gb * 42;
            int i = el / 6, jj = el - i * 6;
            int j = jj + (jj >= i);
            float hv = fmaxf(pp[gb * 7 + i] + qq[gb * 7 + j], 0.f);
            *(u32*)(G + r * H2S + L * 4) = splitpack(hv);
        }
    }
}
// de-interleave 4 packed u32 -> hi short8-half (2 u32) and lo half
__device__ __forceinline__ void unpack4(const uint4& a, u32* ho, u32* lo) {
    ho[0] = __builtin_amdgcn_perm(a.y, a.x, 0x05040100);
    ho[1] = __builtin_amdgcn_perm(a.w, a.z, 0x05040100);
    lo[0] = __builtin_amdgcn_perm(a.y, a.x, 0x07060302);
    lo[1] = __builtin_amdgcn_perm(a.w, a.z, 0x07060302);
}
__device__ __forceinline__ void loadAH(const char* G, int L,
                                       short8& Ah0, short8& Ah1, short8& Al0, short8& Al1) {
    const char* base = G + (L & 15) * H2S + (L >> 4) * 32;
    uint4 a0 = *(const uint4*)(base);
    uint4 a1 = *(const uint4*)(base + 16);
    uint4 b0 = *(const uint4*)(base + 128);
    uint4 b1 = *(const uint4*)(base + 144);
    union { u32 u[4]; short8 s; } h0, h1, l0, l1;
    unpack4(a0, &h0.u[0], &l0.u[0]);
    unpack4(a1, &h0.u[2], &l0.u[2]);
    unpack4(b0, &h1.u[0], &l1.u[0]);
    unpack4(b1, &h1.u[2], &l1.u[2]);
    Ah0 = h0.s; Al0 = l0.s; Ah1 = h1.s; Al1 = l1.s;
}
// fold chunk cc's S rows into per-node running max (column L)
__device__ __forceinline__ void maxread(const char* Sb, int cc, float* mx, int L) {
#pragma unroll
    for (int r = 0; r < 16; ++r) {
        int e = cc * 16 + r;
        if (e < 84) {
            int gb = (e >= 42) ? 1 : 0;
            int i = (e - gb * 42) / 6;
            float sv = *(const float*)(Sb + r * SSTR + L * 4);
            mx[gb * 7 + i] = fmaxf(mx[gb * 7 + i], sv);
        }
    }
}

// EdgeConv second linear (64->64) + max-agg + bias + relu via MFMA.
// Single-buffered H in W: chunk-c A-frags are consumed into registers before
// chunk c+1 is staged over them (same-wave DS is in-order; compiler inserts
// lgkmcnt waits). B-frags resident in registers. Output X written back into W.
__device__ __forceinline__ void edgeconv_pipe(const u16* __restrict__ ws, int offB,
                                              char* W, char* Sb,
                                              const float* pp, const float* qq,
                                              float vb, int L) {
    short8 Bh[8], Bl[8];            // f = kt*4+nt, resident across all 6 chunks
#pragma unroll
    for (int f = 0; f < 8; ++f) {
        Bh[f] = *(const short8*)(ws + offB + f * 1024 + L * 8);
        Bl[f] = *(const short8*)(ws + offB + f * 1024 + 512 + L * 8);
    }
    float mx[14];
#pragma unroll
    for (int k = 0; k < 14; ++k) mx[k] = -3.0e38f;
    stageH2(W, 0, pp, qq, L);
    short8 Ah0, Ah1, Al0, Al1;
    loadAH(W, L, Ah0, Ah1, Al0, Al1);
#pragma unroll
    for (int c = 0; c < 6; ++c) {
        if (c < 5) stageH2(W, c + 1, pp, qq, L);   // frags for chunk c already in regs
        if (c > 0) maxread(Sb, c - 1, mx, L);      // before S is overwritten
#pragma unroll
        for (int nt = 0; nt < 4; ++nt) {
            f32x4 a1 = {0.f, 0.f, 0.f, 0.f}, a2 = {0.f, 0.f, 0.f, 0.f};
            a1 = mfma1(Ah0, Bh[nt], a1);
            a2 = mfma1(Ah0, Bl[nt], a2);
            a2 = mfma1(Al0, Bh[nt], a2);
            a1 = mfma1(Ah1, Bh[4 + nt], a1);
            a2 = mfma1(Ah1, Bl[4 + nt], a2);
            a2 = mfma1(Al1, Bh[4 + nt], a2);
#pragma unroll
            for (int rr = 0; rr < 4; ++rr)
                *(float*)(Sb + ((L >> 4) * 4 + rr) * SSTR + nt * 64 + (L & 15) * 4) = a1[rr] + a2[rr];
        }
        if (c < 5) loadAH(W, L, Ah0, Ah1, Al0, Al1);   // reads chunk c+1 (DS in-order)
    }
    maxread(Sb, 5, mx, L);
    float xo[14];
#pragma unroll
    for (int k = 0; k < 14; ++k) xo[k] = fmaxf(mx[k] + vb, 0.f);
    writeX64_14(W, L, xo);
}

__global__ __launch_bounds__(128, 4) void gnn_kernel(
    const float* __restrict__ omega, const float* __restrict__ tt, const float* __restrict__ Wf,
    const float* __restrict__ wi1, const float* __restrict__ bi1, const float* __restrict__ bi2,
    const float* __restrict__ bt,
    const float* __restrict__ b1a, const float* __restrict__ b1b,
    const float* __restrict__ b2a, const float* __restrict__ b2b,
    const float* __restrict__ b3a, const float* __restrict__ b3b,
    const u16* __restrict__ ws, float* __restrict__ out)
{
    __shared__ __align__(16) char smem[2 * WREG];   // 17664 B/block
    const int L   = threadIdx.x & 63;
    const int wav = threadIdx.x >> 6;
    const int p   = blockIdx.x * 2 + wav;    // graph pair id, grid covers 25000
    const int g0  = p * 2;
    const int base0 = g0 * 7;                // g1 nodes start at base0+7
    char* W   = smem + wav * WREG;
    char* Sb  = W + 4608;

    // ---- h1 = relu(omega@wi1 + bi1), both graphs (42 contiguous coords) ----
    float omv = (L < 42) ? omega[base0 * 3 + L] : 0.f;
    float vwi10 = wi1[L], vwi11 = wi1[64 + L], vwi12 = wi1[128 + L];
    float vbi1 = bi1[L];
    float h1[14];
#pragma unroll
    for (int k = 0; k < 14; ++k) {
        float a0 = bcast(omv, 3 * k), a1 = bcast(omv, 3 * k + 1), a2 = bcast(omv, 3 * k + 2);
        h1[k] = fmaxf(fmaf(a0, vwi10, fmaf(a1, vwi11, fmaf(a2, vwi12, vbi1))), 0.f);
    }

    // ---- time embedding via MFMA (tile-bug: node n uses t[n % B]) ----
    // E staged in W (bf16 planes, cols 0-31); C -> Sb; xs staged back through W
    // once, then its A-frags (kt=2, constant all kernel) held in registers.
    short8 Ah2, Al2;
    {
        int cc = L & 31;
        float vwf = Wf[cc & 15] * 6.283185307179586f;
        int tb = base0 - (base0 / NB) * NB;        // base0 % NB
#pragma unroll
        for (int k = 0; k < 14; ++k) {
            int ti = tb + k; if (ti >= NB) ti -= NB;
            float pj = tt[ti] * vwf;
            float remb = fmaxf((cc < 16) ? __sinf(pj) : __cosf(pj), 0.f);
            u16 h, l;
            split2(remb, h, l);
            if (L < 32) *(u16*)(W + ROW(k) * HSTR + cc * 2) = h;
            else *(u16*)(W + HLO + ROW(k) * HSTR + cc * 2) = l;
        }
        short8 Eh = *(const short8*)(W + (L & 15) * HSTR + (L >> 4) * 16);
        short8 El = *(const short8*)(W + HLO + (L & 15) * HSTR + (L >> 4) * 16);
#pragma unroll
        for (int nt = 0; nt < 2; ++nt) {
            short8 bh = *(const short8*)(ws + OFF_WT + nt * 1024 + L * 8);
            short8 bl = *(const short8*)(ws + OFF_WT + nt * 1024 + 512 + L * 8);
            f32x4 acc = {0.f, 0.f, 0.f, 0.f};
            acc = mfma3(Eh, El, bh, bl, acc);
#pragma unroll
            for (int rr = 0; rr < 4; ++rr)
                *(float*)(Sb + ((L >> 4) * 4 + rr) * SSTR + nt * 64 + (L & 15) * 4) = acc[rr];
        }
        float vbt = bt[cc];
#pragma unroll
        for (int k = 0; k < 14; ++k) {
            float xv = fmaxf(*(const float*)(Sb + ROW(k) * SSTR + cc * 4) + vbt, 0.f);
            u16 h, l;
            split2(xv, h, l);
            if (L < 32) *(u16*)(W + ROW(k) * HSTR + cc * 2) = h;
            else *(u16*)(W + HLO + ROW(k) * HSTR + cc * 2) = l;
        }
        // xs A-frag (cols 0-31 of W == k 64..95), resident for L2a/L3a
        Ah2 = *(const short8*)(W + (L & 15) * HSTR + (L >> 4) * 16);
        Al2 = *(const short8*)(W + HLO + (L & 15) * HSTR + (L >> 4) * 16);
    }

    short8 Ah[3], Al[3];
    float pp[14], qq[14];

    // ---- init: x0 = h1 @ wi2 + bi2  (X: W, S: Sb, X back to W) ----
    writeX64_14(W, L, h1);
    loadA2(W, L, Ah, Al);
    lin_pass<2, 4>(ws, OFF_I, 0, Ah, Al, Sb, L);
    {
        float xh[14];
        readS14(Sb, L, xh);
        float vbi2 = bi2[L];
#pragma unroll
        for (int k = 0; k < 14; ++k) xh[k] += vbi2;
        writeX64_14(W, L, xh);
    }

    // ---- L1a (K=64): A from W, S in Sb ----
    loadA2(W, L, Ah, Al);
    lin_pass<2, 8>(ws, OFF_1A, 0, Ah, Al, Sb, L);
    readS14(Sb, L, pp);
    lin_pass<2, 8>(ws, OFF_1A, 4, Ah, Al, Sb, L);
    readS14(Sb, L, qq);
    float vb1a = b1a[L];
#pragma unroll
    for (int k = 0; k < 14; ++k) pp[k] = pp[k] + vb1a - qq[k];
    // ---- L1b (X out -> W) ----
    edgeconv_pipe(ws, OFF_1B, W, Sb, pp, qq, b1b[L], L);

    // ---- L2a (K=96: [x | xs]) ----
    loadA2(W, L, Ah, Al);
    Ah[2] = Ah2; Al[2] = Al2;
    lin_pass<3, 8>(ws, OFF_2A, 0, Ah, Al, Sb, L);
    readS14(Sb, L, pp);
    lin_pass<3, 8>(ws, OFF_2A, 4, Ah, Al, Sb, L);
    readS14(Sb, L, qq);
    float vb2a = b2a[L];
#pragma unroll
    for (int k = 0; k < 14; ++k) pp[k] = pp[k] + vb2a - qq[k];
    // ---- L2b ----
    edgeconv_pipe(ws, OFF_2B, W, Sb, pp, qq, b2b[L], L);

    // ---- L3a (K=96) ----
    loadA2(W, L, Ah, Al);
    Ah[2] = Ah2; Al[2] = Al2;
    lin_pass<3, 8>(ws, OFF_3A, 0, Ah, Al, Sb, L);
    readS14(Sb, L, pp);
    lin_pass<3, 8>(ws, OFF_3A, 4, Ah, Al, Sb, L);
    readS14(Sb, L, qq);
    float vb3a = b3a[L];
#pragma unroll
    for (int k = 0; k < 14; ++k) pp[k] = pp[k] + vb3a - qq[k];

    // ---- L3b (64->3) via MFMA (single-buffered) + max + /(std+1e-7) ----
    {
        short8 B0h = *(const short8*)(ws + OFF_3B + L * 8);
        short8 B0l = *(const short8*)(ws + OFF_3B + 512 + L * 8);
        short8 B1h = *(const short8*)(ws + OFF_3B + 1024 + L * 8);
        short8 B1l = *(const short8*)(ws + OFF_3B + 1536 + L * 8);
        stageH2(W, 0, pp, qq, L);
        short8 Ah0, Ah1, Al0, Al1;
        loadAH(W, L, Ah0, Ah1, Al0, Al1);
#pragma unroll
        for (int c = 0; c < 6; ++c) {
            if (c < 5) stageH2(W, c + 1, pp, qq, L);
            f32x4 a1 = {0.f, 0.f, 0.f, 0.f}, a2 = {0.f, 0.f, 0.f, 0.f};
            a1 = mfma1(Ah0, B0h, a1);
            a2 = mfma1(Ah0, B0l, a2);
            a2 = mfma1(Al0, B0h, a2);
            a1 = mfma1(Ah1, B1h, a1);
            a2 = mfma1(Ah1, B1l, a2);
            a2 = mfma1(Al1, B1h, a2);
            if ((L & 15) < 3) {       // compact strip: row e (96), stride 16B, col 0..2
#pragma unroll
                for (int rr = 0; rr < 4; ++rr)
                    *(float*)(Sb + (c * 16 + (L >> 4) * 4 + rr) * 16 + (L & 15) * 4) = a1[rr] + a2[rr];
            }
            if (c < 5) loadAH(W, L, Ah0, Ah1, Al0, Al1);
        }
        if (L < 42) {                 // lanes 0-20: g0; 21-41: g1
            int gb = (L >= 21) ? 1 : 0;
            int ll = L - gb * 21;
            int i = ll / 3, col = ll - i * 3;
            int e0 = gb * 42 + i * 6;
            float m = -3.0e38f;
#pragma unroll
            for (int e6 = 0; e6 < 6; ++e6)
                m = fmaxf(m, *(const float*)(Sb + (e0 + e6) * 16 + col * 4));
            m += b3b[col];
            float tg = tt[g0 + gb];   // std uses t[n // 7]
            float stdv = sqrtf((exp2f(tg * 9.287712379549448f) - 1.0f) * 0.15533740282828987f);
            out[base0 * 3 + L] = m / (stdv + 1e-7f);   // contiguous 42 outputs
        }
    }
}

extern "C" void kernel_launch(void* const* d_in, const int* in_sizes, int n_in,
                              void* d_out, int out_size, void* d_ws, size_t ws_size,
                              hipStream_t stream) {
    const float* omega = (const float*)d_in[0];
    // d_in[1] edge_index unused (fixed fully-connected); d_in[3] num_objs == 7
    const float* tt  = (const float*)d_in[2];
    const float* Wf  = (const float*)d_in[4];
    const float* wi1 = (const float*)d_in[5];
    const float* bi1 = (const float*)d_in[6];
    const float* wi2 = (const float*)d_in[7];
    const float* bi2 = (const float*)d_in[8];
    const float* wt  = (const float*)d_in[9];
    const float* bt  = (const float*)d_in[10];
    const float* w1a = (const float*)d_in[11];
    const float* b1a = (const float*)d_in[12];
    const float* w1b = (const float*)d_in[13];
    const float* b1b = (const float*)d_in[14];
    const float* w2a = (const float*)d_in[15];
    const float* b2a = (const float*)d_in[16];
    const float* w2b = (const float*)d_in[17];
    const float* b2b = (const float*)d_in[18];
    const float* w3a = (const float*)d_in[19];
    const float* b3a = (const float*)d_in[20];
    const float* w3b = (const float*)d_in[21];
    const float* b3b = (const float*)d_in[22];
    u16* ws = (u16*)d_ws;   // needs 188416 bytes

    pack_kernel<<<dim3(92, 8), dim3(128), 0, stream>>>(wi2, w1a, w2a, w3a, w1b, w2b, wt, w3b, ws);
    gnn_kernel<<<dim3(12500), dim3(128), 0, stream>>>(
        omega, tt, Wf, wi1, bi1, bi2, bt,
        b1a, b1b, b2a, b2b, b3a, b3b, ws, (float*)d_out);
}

// Round 2
// 421.767 us; speedup vs baseline: 1.6149x; 1.6149x over previous
//
#include <hip/hip_runtime.h>

// ScoreNetGNN: B=50000 graphs x 7 nodes, fully-connected (42 edges/graph).
// R6: MFMA pipeline (16x16x32 bf16 split hi+lo). R7: strides/LDS. R8: two
// graphs/wave. R9: 128-thr blocks. R11: two-chain accum + pipelined edgeconv.
// R12: truncation-split, resident edge B-frags. R13: parallel pack + packed-H.
// R14: LDS/wave 15744 -> 8832 (XS2 -> resident regs; H single-buffered in W).
//   Occupancy 22.6 -> 43.5% confirmed, BUT __launch_bounds__(128,4) pinned
//   VGPR to 64 -> massive scratch spills (FETCH 793MB, WRITE 1.3GB) -> 681us.
// R15 (this): same LDS layout, launch_bounds min-waves arg REMOVED. Natural
//   VGPR ~104-120 <= 128 already permits 4 waves/SIMD; LDS (17920B/block)
//   allows 9 blocks/CU, so VGPR binds at 16 waves/CU (was LDS-bound 10).
// f32 I/O hardcoded (R3 counters: WRITE_SIZE = 4 B/elem).

#define NB 50000

typedef unsigned short u16;
typedef unsigned int u32;
typedef short short8 __attribute__((ext_vector_type(8)));
typedef float f32x4 __attribute__((ext_vector_type(4)));

// d_ws fragment offsets (u16 units). frag stride 1024 u16 (hi 512 | lo 512),
// lane entry = 8 u16 (16B). Total 94208 u16 = 188416 bytes.
#define OFF_I  0
#define OFF_1A 8192
#define OFF_2A 24576
#define OFF_3A 49152
#define OFF_1B 73728
#define OFF_2B 81920
#define OFF_WT 90112
#define OFF_3B 92160

// LDS per-wave geometry (bytes). W dual-use region (4608B):
//  - as X: 16 rows x 64 bf16 @ stride 144, hi [0,2304) lo [2304,4608)
//  - as H: 16 rows x 64 packed u32 @ stride 272 (68 dw -> <=2-way, free)
//  - transiently as E/xs staging (cols 0-31) during the embedding phase
// Sb: f32 C @ stride 264.
#define HSTR 144
#define HLO  2304
#define H2S  272
#define SSTR 264
#define WREG 8832    // W 4608 + Sb 4224

__device__ __forceinline__ float b2f(u16 u) {
    return __uint_as_float(((u32)u) << 16);
}
__device__ __forceinline__ u16 f2b(float f) {
    u32 u = __float_as_uint(f);
    u += 0x7FFFu + ((u >> 16) & 1u);   // RNE
    return (u16)(u >> 16);
}
// split v into bf16 hi (truncated, v-hi exact) + bf16 lo (RNE of residual)
__device__ __forceinline__ void split2(float v, u16& h, u16& l) {
    u32 u = __float_as_uint(v);
    h = (u16)(u >> 16);
    float d = v - __uint_as_float(u & 0xffff0000u);
    l = f2b(d);
}
// packed u32: low16 = hi(trunc), high16 = lo(RNE)
__device__ __forceinline__ u32 splitpack(float v) {
    u32 u = __float_as_uint(v);
    float d = v - __uint_as_float(u & 0xffff0000u);
    u32 r = __float_as_uint(d);
    r += 0x7FFFu + ((r >> 16) & 1u);
    return __builtin_amdgcn_perm(r, u, 0x07060302);  // [u.b2,u.b3,r.b2,r.b3]
}
__device__ __forceinline__ float bcast(float v, int l) {
    return __uint_as_float(__builtin_amdgcn_readlane(__float_as_uint(v), l));
}

// ---- setup: pack weights into split-bf16 MFMA B-fragments ----
// grid (92, 8): blockIdx.y = element j within lane entry; 128 thr = half x lane.
__global__ __launch_bounds__(128) void pack_kernel(
    const float* __restrict__ wi2, const float* __restrict__ w1a,
    const float* __restrict__ w2a, const float* __restrict__ w3a,
    const float* __restrict__ w1b, const float* __restrict__ w2b,
    const float* __restrict__ wt,  const float* __restrict__ w3b,
    u16* __restrict__ ws)
{
    int blk = blockIdx.x;
    int j    = blockIdx.y;
    int half = threadIdx.x >> 6;          // 0 = hi, 1 = lo
    int lane = threadIdx.x & 63;
    float v;
    u16* dst;
    if (blk < 88) {
        const float* src; int NT, qoff, obase, frag;
        if (blk < 8)       { src = wi2; NT = 4; qoff = 0;  obase = OFF_I;  frag = blk;      }
        else if (blk < 24) { src = w1a; NT = 8; qoff = 64; obase = OFF_1A; frag = blk - 8;  }
        else if (blk < 48) { src = w2a; NT = 8; qoff = 96; obase = OFF_2A; frag = blk - 24; }
        else if (blk < 72) { src = w3a; NT = 8; qoff = 96; obase = OFF_3A; frag = blk - 48; }
        else if (blk < 80) { src = w1b; NT = 4; qoff = 0;  obase = OFF_1B; frag = blk - 72; }
        else               { src = w2b; NT = 4; qoff = 0;  obase = OFF_2B; frag = blk - 80; }
        int kt = frag / NT, nt = frag % NT;
        int k = kt * 32 + (lane >> 4) * 8 + j;
        int n = nt * 16 + (lane & 15);
        int idx = (n < 64) ? (k * 64 + n) : ((qoff + k) * 64 + (n - 64));
        v = src[idx];
        dst = ws + obase + frag * 1024 + half * 512 + lane * 8 + j;
    } else if (blk < 90) {               // wt (32,32): 2 n-frags
        int frag = blk - 88;
        int k = (lane >> 4) * 8 + j;
        int n = frag * 16 + (lane & 15);
        v = wt[k * 32 + n];
        dst = ws + OFF_WT + frag * 1024 + half * 512 + lane * 8 + j;
    } else {                             // w3b (64,3): 2 k-frags, cols 3..15 = 0
        int frag = blk - 90;
        int k = frag * 32 + (lane >> 4) * 8 + j;
        int n = lane & 15;
        v = (n < 3) ? w3b[k * 3 + n] : 0.f;
        dst = ws + OFF_3B + frag * 1024 + half * 512 + lane * 8 + j;
    }
    u16 hi = f2b(v);
    *dst = (half == 0) ? hi : f2b(v - b2f(hi));
}

__device__ __forceinline__ f32x4 mfma1(short8 a, short8 b, f32x4 acc) {
    return __builtin_amdgcn_mfma_f32_16x16x32_bf16(a, b, acc, 0, 0, 0);
}
__device__ __forceinline__ f32x4 mfma3(short8 ah, short8 al, short8 bh, short8 bl, f32x4 acc) {
    acc = mfma1(ah, bh, acc);
    acc = mfma1(ah, bl, acc);
    acc = mfma1(al, bh, acc);
    return acc;   // lo*lo dropped
}

// node k (0..13) -> row (g0 rows 0-6, g1 rows 8-14; rows 7,15 stale/unread)
#define ROW(k) ((k) < 7 ? (k) : (k) + 1)

// write 14 node values (64 cols) into region G as X (bf16 hi/lo planes)
__device__ __forceinline__ void writeX64_14(char* G, int L, const float* v) {
#pragma unroll
    for (int k = 0; k < 14; ++k) {
        int r = ROW(k);
        u16 h, l;
        split2(v[k], h, l);
        *(u16*)(G + r * HSTR + L * 2) = h;
        *(u16*)(G + HLO + r * HSTR + L * 2) = l;
    }
}
// A-frags kt 0,1 from G (cols 0-63); kt 2 (xs, cols 64-95) is register-resident.
__device__ __forceinline__ void loadA2(const char* G, int L, short8* Ah, short8* Al) {
#pragma unroll
    for (int kt = 0; kt < 2; ++kt) {
        Ah[kt] = *(const short8*)(G + (L & 15) * HSTR + kt * 64 + (L >> 4) * 16);
        Al[kt] = *(const short8*)(G + HLO + (L & 15) * HSTR + kt * 64 + (L >> 4) * 16);
    }
}
// One 4-N-tile GEMM pass: S[row][col 0..63] = A(16xK) @ B(Kx64).
template<int KT, int NT>
__device__ __forceinline__ void lin_pass(const u16* __restrict__ ws, int off, int nt0,
                                         const short8* Ah, const short8* Al,
                                         char* Sg, int L) {
#pragma unroll
    for (int ntc = 0; ntc < 4; ++ntc) {
        f32x4 a1 = {0.f, 0.f, 0.f, 0.f}, a2 = {0.f, 0.f, 0.f, 0.f};
#pragma unroll
        for (int kt = 0; kt < KT; ++kt) {
            int f = kt * NT + nt0 + ntc;
            short8 bh = *(const short8*)(ws + off + f * 1024 + L * 8);
            short8 bl = *(const short8*)(ws + off + f * 1024 + 512 + L * 8);
            a1 = mfma1(Ah[kt], bh, a1);
            a2 = mfma1(Ah[kt], bl, a2);
            a2 = mfma1(Al[kt], bh, a2);
        }
#pragma unroll
        for (int rr = 0; rr < 4; ++rr)   // C: row=(L>>4)*4+rr, col=ntc*16+(L&15)
            *(float*)(Sg + ((L >> 4) * 4 + rr) * SSTR + ntc * 64 + (L & 15) * 4) = a1[rr] + a2[rr];
    }
}
__device__ __forceinline__ void readS14(const char* Sg, int L, float* o) {
#pragma unroll
    for (int k = 0; k < 14; ++k) o[k] = *(const float*)(Sg + ROW(k) * SSTR + L * 4);
}
// stage 16 edge rows (chunk c of 6; 84 real edges) as PACKED u32 per element
__device__ __forceinline__ void stageH2(char* G, int c, const float* pp, const float* qq, int L) {
#pragma unroll
    for (int r = 0; r < 16; ++r) {
        int e = c * 16 + r;
        if (e < 84) {
            int gb = (e >= 42) ? 1 : 0;
            int el = e - gb * 42;
            int i = el / 6, jj = el - i * 6;
            int j = jj + (jj >= i);
            float hv = fmaxf(pp[gb * 7 + i] + qq[gb * 7 + j], 0.f);
            *(u32*)(G + r * H2S + L * 4) = splitpack(hv);
        }
    }
}
// de-interleave 4 packed u32 -> hi short8-half (2 u32) and lo half
__device__ __forceinline__ void unpack4(const uint4& a, u32* ho, u32* lo) {
    ho[0] = __builtin_amdgcn_perm(a.y, a.x, 0x05040100);
    ho[1] = __builtin_amdgcn_perm(a.w, a.z, 0x05040100);
    lo[0] = __builtin_amdgcn_perm(a.y, a.x, 0x07060302);
    lo[1] = __builtin_amdgcn_perm(a.w, a.z, 0x07060302);
}
__device__ __forceinline__ void loadAH(const char* G, int L,
                                       short8& Ah0, short8& Ah1, short8& Al0, short8& Al1) {
    const char* base = G + (L & 15) * H2S + (L >> 4) * 32;
    uint4 a0 = *(const uint4*)(base);
    uint4 a1 = *(const uint4*)(base + 16);
    uint4 b0 = *(const uint4*)(base + 128);
    uint4 b1 = *(const uint4*)(base + 144);
    union { u32 u[4]; short8 s; } h0, h1, l0, l1;
    unpack4(a0, &h0.u[0], &l0.u[0]);
    unpack4(a1, &h0.u[2], &l0.u[2]);
    unpack4(b0, &h1.u[0], &l1.u[0]);
    unpack4(b1, &h1.u[2], &l1.u[2]);
    Ah0 = h0.s; Al0 = l0.s; Ah1 = h1.s; Al1 = l1.s;
}
// fold chunk cc's S rows into per-node running max (column L)
__device__ __forceinline__ void maxread(const char* Sb, int cc, float* mx, int L) {
#pragma unroll
    for (int r = 0; r < 16; ++r) {
        int e = cc * 16 + r;
        if (e < 84) {
            int gb = (e >= 42) ? 1 : 0;
            int i = (e - gb * 42) / 6;
            float sv = *(const float*)(Sb + r * SSTR + L * 4);
            mx[gb * 7 + i] = fmaxf(mx[gb * 7 + i], sv);
        }
    }
}

// EdgeConv second linear (64->64) + max-agg + bias + relu via MFMA.
// Single-buffered H in W: chunk-c A-frags are consumed into registers before
// chunk c+1 is staged over them (same-wave DS is in-order; compiler inserts
// lgkmcnt waits). B-frags resident in registers. Output X written back into W.
__device__ __forceinline__ void edgeconv_pipe(const u16* __restrict__ ws, int offB,
                                              char* W, char* Sb,
                                              const float* pp, const float* qq,
                                              float vb, int L) {
    short8 Bh[8], Bl[8];            // f = kt*4+nt, resident across all 6 chunks
#pragma unroll
    for (int f = 0; f < 8; ++f) {
        Bh[f] = *(const short8*)(ws + offB + f * 1024 + L * 8);
        Bl[f] = *(const short8*)(ws + offB + f * 1024 + 512 + L * 8);
    }
    float mx[14];
#pragma unroll
    for (int k = 0; k < 14; ++k) mx[k] = -3.0e38f;
    stageH2(W, 0, pp, qq, L);
    short8 Ah0, Ah1, Al0, Al1;
    loadAH(W, L, Ah0, Ah1, Al0, Al1);
#pragma unroll
    for (int c = 0; c < 6; ++c) {
        if (c < 5) stageH2(W, c + 1, pp, qq, L);   // frags for chunk c already in regs
        if (c > 0) maxread(Sb, c - 1, mx, L);      // before S is overwritten
#pragma unroll
        for (int nt = 0; nt < 4; ++nt) {
            f32x4 a1 = {0.f, 0.f, 0.f, 0.f}, a2 = {0.f, 0.f, 0.f, 0.f};
            a1 = mfma1(Ah0, Bh[nt], a1);
            a2 = mfma1(Ah0, Bl[nt], a2);
            a2 = mfma1(Al0, Bh[nt], a2);
            a1 = mfma1(Ah1, Bh[4 + nt], a1);
            a2 = mfma1(Ah1, Bl[4 + nt], a2);
            a2 = mfma1(Al1, Bh[4 + nt], a2);
#pragma unroll
            for (int rr = 0; rr < 4; ++rr)
                *(float*)(Sb + ((L >> 4) * 4 + rr) * SSTR + nt * 64 + (L & 15) * 4) = a1[rr] + a2[rr];
        }
        if (c < 5) loadAH(W, L, Ah0, Ah1, Al0, Al1);   // reads chunk c+1 (DS in-order)
    }
    maxread(Sb, 5, mx, L);
    float xo[14];
#pragma unroll
    for (int k = 0; k < 14; ++k) xo[k] = fmaxf(mx[k] + vb, 0.f);
    writeX64_14(W, L, xo);
}

__global__ __launch_bounds__(128) void gnn_kernel(
    const float* __restrict__ omega, const float* __restrict__ tt, const float* __restrict__ Wf,
    const float* __restrict__ wi1, const float* __restrict__ bi1, const float* __restrict__ bi2,
    const float* __restrict__ bt,
    const float* __restrict__ b1a, const float* __restrict__ b1b,
    const float* __restrict__ b2a, const float* __restrict__ b2b,
    const float* __restrict__ b3a, const float* __restrict__ b3b,
    const u16* __restrict__ ws, float* __restrict__ out)
{
    __shared__ __align__(16) char smem[2 * WREG];   // 17664 B/block
    const int L   = threadIdx.x & 63;
    const int wav = threadIdx.x >> 6;
    const int p   = blockIdx.x * 2 + wav;    // graph pair id, grid covers 25000
    const int g0  = p * 2;
    const int base0 = g0 * 7;                // g1 nodes start at base0+7
    char* W   = smem + wav * WREG;
    char* Sb  = W + 4608;

    // ---- h1 = relu(omega@wi1 + bi1), both graphs (42 contiguous coords) ----
    float omv = (L < 42) ? omega[base0 * 3 + L] : 0.f;
    float vwi10 = wi1[L], vwi11 = wi1[64 + L], vwi12 = wi1[128 + L];
    float vbi1 = bi1[L];
    float h1[14];
#pragma unroll
    for (int k = 0; k < 14; ++k) {
        float a0 = bcast(omv, 3 * k), a1 = bcast(omv, 3 * k + 1), a2 = bcast(omv, 3 * k + 2);
        h1[k] = fmaxf(fmaf(a0, vwi10, fmaf(a1, vwi11, fmaf(a2, vwi12, vbi1))), 0.f);
    }

    // ---- time embedding via MFMA (tile-bug: node n uses t[n % B]) ----
    // E staged in W (bf16 planes, cols 0-31); C -> Sb; xs staged back through W
    // once, then its A-frags (kt=2, constant all kernel) held in registers.
    short8 Ah2, Al2;
    {
        int cc = L & 31;
        float vwf = Wf[cc & 15] * 6.283185307179586f;
        int tb = base0 - (base0 / NB) * NB;        // base0 % NB
#pragma unroll
        for (int k = 0; k < 14; ++k) {
            int ti = tb + k; if (ti >= NB) ti -= NB;
            float pj = tt[ti] * vwf;
            float remb = fmaxf((cc < 16) ? __sinf(pj) : __cosf(pj), 0.f);
            u16 h, l;
            split2(remb, h, l);
            if (L < 32) *(u16*)(W + ROW(k) * HSTR + cc * 2) = h;
            else *(u16*)(W + HLO + ROW(k) * HSTR + cc * 2) = l;
        }
        short8 Eh = *(const short8*)(W + (L & 15) * HSTR + (L >> 4) * 16);
        short8 El = *(const short8*)(W + HLO + (L & 15) * HSTR + (L >> 4) * 16);
#pragma unroll
        for (int nt = 0; nt < 2; ++nt) {
            short8 bh = *(const short8*)(ws + OFF_WT + nt * 1024 + L * 8);
            short8 bl = *(const short8*)(ws + OFF_WT + nt * 1024 + 512 + L * 8);
            f32x4 acc = {0.f, 0.f, 0.f, 0.f};
            acc = mfma3(Eh, El, bh, bl, acc);
#pragma unroll
            for (int rr = 0; rr < 4; ++rr)
                *(float*)(Sb + ((L >> 4) * 4 + rr) * SSTR + nt * 64 + (L & 15) * 4) = acc[rr];
        }
        float vbt = bt[cc];
#pragma unroll
        for (int k = 0; k < 14; ++k) {
            float xv = fmaxf(*(const float*)(Sb + ROW(k) * SSTR + cc * 4) + vbt, 0.f);
            u16 h, l;
            split2(xv, h, l);
            if (L < 32) *(u16*)(W + ROW(k) * HSTR + cc * 2) = h;
            else *(u16*)(W + HLO + ROW(k) * HSTR + cc * 2) = l;
        }
        // xs A-frag (cols 0-31 of W == k 64..95), resident for L2a/L3a
        Ah2 = *(const short8*)(W + (L & 15) * HSTR + (L >> 4) * 16);
        Al2 = *(const short8*)(W + HLO + (L & 15) * HSTR + (L >> 4) * 16);
    }

    short8 Ah[3], Al[3];
    float pp[14], qq[14];

    // ---- init: x0 = h1 @ wi2 + bi2  (X: W, S: Sb, X back to W) ----
    writeX64_14(W, L, h1);
    loadA2(W, L, Ah, Al);
    lin_pass<2, 4>(ws, OFF_I, 0, Ah, Al, Sb, L);
    {
        float xh[14];
        readS14(Sb, L, xh);
        float vbi2 = bi2[L];
#pragma unroll
        for (int k = 0; k < 14; ++k) xh[k] += vbi2;
        writeX64_14(W, L, xh);
    }

    // ---- L1a (K=64): A from W, S in Sb ----
    loadA2(W, L, Ah, Al);
    lin_pass<2, 8>(ws, OFF_1A, 0, Ah, Al, Sb, L);
    readS14(Sb, L, pp);
    lin_pass<2, 8>(ws, OFF_1A, 4, Ah, Al, Sb, L);
    readS14(Sb, L, qq);
    float vb1a = b1a[L];
#pragma unroll
    for (int k = 0; k < 14; ++k) pp[k] = pp[k] + vb1a - qq[k];
    // ---- L1b (X out -> W) ----
    edgeconv_pipe(ws, OFF_1B, W, Sb, pp, qq, b1b[L], L);

    // ---- L2a (K=96: [x | xs]) ----
    loadA2(W, L, Ah, Al);
    Ah[2] = Ah2; Al[2] = Al2;
    lin_pass<3, 8>(ws, OFF_2A, 0, Ah, Al, Sb, L);
    readS14(Sb, L, pp);
    lin_pass<3, 8>(ws, OFF_2A, 4, Ah, Al, Sb, L);
    readS14(Sb, L, qq);
    float vb2a = b2a[L];
#pragma unroll
    for (int k = 0; k < 14; ++k) pp[k] = pp[k] + vb2a - qq[k];
    // ---- L2b ----
    edgeconv_pipe(ws, OFF_2B, W, Sb, pp, qq, b2b[L], L);

    // ---- L3a (K=96) ----
    loadA2(W, L, Ah, Al);
    Ah[2] = Ah2; Al[2] = Al2;
    lin_pass<3, 8>(ws, OFF_3A, 0, Ah, Al, Sb, L);
    readS14(Sb, L, pp);
    lin_pass<3, 8>(ws, OFF_3A, 4, Ah, Al, Sb, L);
    readS14(Sb, L, qq);
    float vb3a = b3a[L];
#pragma unroll
    for (int k = 0; k < 14; ++k) pp[k] = pp[k] + vb3a - qq[k];

    // ---- L3b (64->3) via MFMA (single-buffered) + max + /(std+1e-7) ----
    {
        short8 B0h = *(const short8*)(ws + OFF_3B + L * 8);
        short8 B0l = *(const short8*)(ws + OFF_3B + 512 + L * 8);
        short8 B1h = *(const short8*)(ws + OFF_3B + 1024 + L * 8);
        short8 B1l = *(const short8*)(ws + OFF_3B + 1536 + L * 8);
        stageH2(W, 0, pp, qq, L);
        short8 Ah0, Ah1, Al0, Al1;
        loadAH(W, L, Ah0, Ah1, Al0, Al1);
#pragma unroll
        for (int c = 0; c < 6; ++c) {
            if (c < 5) stageH2(W, c + 1, pp, qq, L);
            f32x4 a1 = {0.f, 0.f, 0.f, 0.f}, a2 = {0.f, 0.f, 0.f, 0.f};
            a1 = mfma1(Ah0, B0h, a1);
            a2 = mfma1(Ah0, B0l, a2);
            a2 = mfma1(Al0, B0h, a2);
            a1 = mfma1(Ah1, B1h, a1);
            a2 = mfma1(Ah1, B1l, a2);
            a2 = mfma1(Al1, B1h, a2);
            if ((L & 15) < 3) {       // compact strip: row e (96), stride 16B, col 0..2
#pragma unroll
                for (int rr = 0; rr < 4; ++rr)
                    *(float*)(Sb + (c * 16 + (L >> 4) * 4 + rr) * 16 + (L & 15) * 4) = a1[rr] + a2[rr];
            }
            if (c < 5) loadAH(W, L, Ah0, Ah1, Al0, Al1);
        }
        if (L < 42) {                 // lanes 0-20: g0; 21-41: g1
            int gb = (L >= 21) ? 1 : 0;
            int ll = L - gb * 21;
            int i = ll / 3, col = ll - i * 3;
            int e0 = gb * 42 + i * 6;
            float m = -3.0e38f;
#pragma unroll
            for (int e6 = 0; e6 < 6; ++e6)
                m = fmaxf(m, *(const float*)(Sb + (e0 + e6) * 16 + col * 4));
            m += b3b[col];
            float tg = tt[g0 + gb];   // std uses t[n // 7]
            float stdv = sqrtf((exp2f(tg * 9.287712379549448f) - 1.0f) * 0.15533740282828987f);
            out[base0 * 3 + L] = m / (stdv + 1e-7f);   // contiguous 42 outputs
        }
    }
}

extern "C" void kernel_launch(void* const* d_in, const int* in_sizes, int n_in,
                              void* d_out, int out_size, void* d_ws, size_t ws_size,
                              hipStream_t stream) {
    const float* omega = (const float*)d_in[0];
    // d_in[1] edge_index unused (fixed fully-connected); d_in[3] num_objs == 7
    const float* tt  = (const float*)d_in[2];
    const float* Wf  = (const float*)d_in[4];
    const float* wi1 = (const float*)d_in[5];
    const float* bi1 = (const float*)d_in[6];
    const float* wi2 = (const float*)d_in[7];
    const float* bi2 = (const float*)d_in[8];
    const float* wt  = (const float*)d_in[9];
    const float* bt  = (const float*)d_in[10];
    const float* w1a = (const float*)d_in[11];
    const float* b1a = (const float*)d_in[12];
    const float* w1b = (const float*)d_in[13];
    const float* b1b = (const float*)d_in[14];
    const float* w2a = (const float*)d_in[15];
    const float* b2a = (const float*)d_in[16];
    const float* w2b = (const float*)d_in[17];
    const float* b2b = (const float*)d_in[18];
    const float* w3a = (const float*)d_in[19];
    const float* b3a = (const float*)d_in[20];
    const float* w3b = (const float*)d_in[21];
    const float* b3b = (const float*)d_in[22];
    u16* ws = (u16*)d_ws;   // needs 188416 bytes

    pack_kernel<<<dim3(92, 8), dim3(128), 0, stream>>>(wi2, w1a, w2a, w3a, w1b, w2b, wt, w3b, ws);
    gnn_kernel<<<dim3(12500), dim3(128), 0, stream>>>(
        omega, tt, Wf, wi1, bi1, bi2, bt,
        b1a, b1b, b2a, b2b, b3a, b3b, ws, (float*)d_out);
}

// Round 3
// 415.445 us; speedup vs baseline: 1.6394x; 1.0152x over previous
//
#include <hip/hip_runtime.h>

// ScoreNetGNN: B=50000 graphs x 7 nodes, fully-connected (42 edges/graph).
// R6: MFMA pipeline (16x16x32 bf16 split hi+lo). R7: strides/LDS. R8: two
// graphs/wave. R9: 128-thr blocks. R11: two-chain accum + pipelined edgeconv.
// R12: truncation-split, resident edge B-frags. R13: parallel pack + packed-H.
// R14: LDS/wave -> 8832; launch_bounds(128,4) over-pinned VGPR=64 -> spills.
// R15: bounds removed. Occupancy STUCK at 22% =~ 2 waves/SIMD cap: total
//   unified-file allocation (arch 108 + AGPR region for resident frags) >170.
//   Across R12-R15, achieved occupancy == ~88% of the register wave-cap.
// R16 (this): cut total reg allocation under 170 -> 3 waves/SIMD:
//   (1) Bh[8]/Bl[8] (64 VGPRs, resident across edgeconv) eliminated; B-frags
//       reloaded per (chunk,nt) from ws. 16KB B-region/edgeconv, re-read 6x,
//       L1-resident -> cheap VMEM hidden by 6-MFMA body + co-resident waves.
//   (2) __launch_bounds__(128,3): target 170 total (ABOVE the ~150 pressure,
//       unlike R14's 128-target) - constrains scheduler ballooning, no spill.
// f32 I/O hardcoded (R3 counters: WRITE_SIZE = 4 B/elem).

#define NB 50000

typedef unsigned short u16;
typedef unsigned int u32;
typedef short short8 __attribute__((ext_vector_type(8)));
typedef float f32x4 __attribute__((ext_vector_type(4)));

// d_ws fragment offsets (u16 units). frag stride 1024 u16 (hi 512 | lo 512),
// lane entry = 8 u16 (16B). Total 94208 u16 = 188416 bytes.
#define OFF_I  0
#define OFF_1A 8192
#define OFF_2A 24576
#define OFF_3A 49152
#define OFF_1B 73728
#define OFF_2B 81920
#define OFF_WT 90112
#define OFF_3B 92160

// LDS per-wave geometry (bytes). W dual-use region (4608B):
//  - as X: 16 rows x 64 bf16 @ stride 144, hi [0,2304) lo [2304,4608)
//  - as H: 16 rows x 64 packed u32 @ stride 272 (68 dw -> <=2-way, free)
//  - transiently as E/xs staging (cols 0-31) during the embedding phase
// Sb: f32 C @ stride 264.
#define HSTR 144
#define HLO  2304
#define H2S  272
#define SSTR 264
#define WREG 8832    // W 4608 + Sb 4224

__device__ __forceinline__ float b2f(u16 u) {
    return __uint_as_float(((u32)u) << 16);
}
__device__ __forceinline__ u16 f2b(float f) {
    u32 u = __float_as_uint(f);
    u += 0x7FFFu + ((u >> 16) & 1u);   // RNE
    return (u16)(u >> 16);
}
// split v into bf16 hi (truncated, v-hi exact) + bf16 lo (RNE of residual)
__device__ __forceinline__ void split2(float v, u16& h, u16& l) {
    u32 u = __float_as_uint(v);
    h = (u16)(u >> 16);
    float d = v - __uint_as_float(u & 0xffff0000u);
    l = f2b(d);
}
// packed u32: low16 = hi(trunc), high16 = lo(RNE)
__device__ __forceinline__ u32 splitpack(float v) {
    u32 u = __float_as_uint(v);
    float d = v - __uint_as_float(u & 0xffff0000u);
    u32 r = __float_as_uint(d);
    r += 0x7FFFu + ((r >> 16) & 1u);
    return __builtin_amdgcn_perm(r, u, 0x07060302);  // [u.b2,u.b3,r.b2,r.b3]
}
__device__ __forceinline__ float bcast(float v, int l) {
    return __uint_as_float(__builtin_amdgcn_readlane(__float_as_uint(v), l));
}

// ---- setup: pack weights into split-bf16 MFMA B-fragments ----
// grid (92, 8): blockIdx.y = element j within lane entry; 128 thr = half x lane.
__global__ __launch_bounds__(128) void pack_kernel(
    const float* __restrict__ wi2, const float* __restrict__ w1a,
    const float* __restrict__ w2a, const float* __restrict__ w3a,
    const float* __restrict__ w1b, const float* __restrict__ w2b,
    const float* __restrict__ wt,  const float* __restrict__ w3b,
    u16* __restrict__ ws)
{
    int blk = blockIdx.x;
    int j    = blockIdx.y;
    int half = threadIdx.x >> 6;          // 0 = hi, 1 = lo
    int lane = threadIdx.x & 63;
    float v;
    u16* dst;
    if (blk < 88) {
        const float* src; int NT, qoff, obase, frag;
        if (blk < 8)       { src = wi2; NT = 4; qoff = 0;  obase = OFF_I;  frag = blk;      }
        else if (blk < 24) { src = w1a; NT = 8; qoff = 64; obase = OFF_1A; frag = blk - 8;  }
        else if (blk < 48) { src = w2a; NT = 8; qoff = 96; obase = OFF_2A; frag = blk - 24; }
        else if (blk < 72) { src = w3a; NT = 8; qoff = 96; obase = OFF_3A; frag = blk - 48; }
        else if (blk < 80) { src = w1b; NT = 4; qoff = 0;  obase = OFF_1B; frag = blk - 72; }
        else               { src = w2b; NT = 4; qoff = 0;  obase = OFF_2B; frag = blk - 80; }
        int kt = frag / NT, nt = frag % NT;
        int k = kt * 32 + (lane >> 4) * 8 + j;
        int n = nt * 16 + (lane & 15);
        int idx = (n < 64) ? (k * 64 + n) : ((qoff + k) * 64 + (n - 64));
        v = src[idx];
        dst = ws + obase + frag * 1024 + half * 512 + lane * 8 + j;
    } else if (blk < 90) {               // wt (32,32): 2 n-frags
        int frag = blk - 88;
        int k = (lane >> 4) * 8 + j;
        int n = frag * 16 + (lane & 15);
        v = wt[k * 32 + n];
        dst = ws + OFF_WT + frag * 1024 + half * 512 + lane * 8 + j;
    } else {                             // w3b (64,3): 2 k-frags, cols 3..15 = 0
        int frag = blk - 90;
        int k = frag * 32 + (lane >> 4) * 8 + j;
        int n = lane & 15;
        v = (n < 3) ? w3b[k * 3 + n] : 0.f;
        dst = ws + OFF_3B + frag * 1024 + half * 512 + lane * 8 + j;
    }
    u16 hi = f2b(v);
    *dst = (half == 0) ? hi : f2b(v - b2f(hi));
}

__device__ __forceinline__ f32x4 mfma1(short8 a, short8 b, f32x4 acc) {
    return __builtin_amdgcn_mfma_f32_16x16x32_bf16(a, b, acc, 0, 0, 0);
}
__device__ __forceinline__ f32x4 mfma3(short8 ah, short8 al, short8 bh, short8 bl, f32x4 acc) {
    acc = mfma1(ah, bh, acc);
    acc = mfma1(ah, bl, acc);
    acc = mfma1(al, bh, acc);
    return acc;   // lo*lo dropped
}

// node k (0..13) -> row (g0 rows 0-6, g1 rows 8-14; rows 7,15 stale/unread)
#define ROW(k) ((k) < 7 ? (k) : (k) + 1)

// write 14 node values (64 cols) into region G as X (bf16 hi/lo planes)
__device__ __forceinline__ void writeX64_14(char* G, int L, const float* v) {
#pragma unroll
    for (int k = 0; k < 14; ++k) {
        int r = ROW(k);
        u16 h, l;
        split2(v[k], h, l);
        *(u16*)(G + r * HSTR + L * 2) = h;
        *(u16*)(G + HLO + r * HSTR + L * 2) = l;
    }
}
// A-frags kt 0,1 from G (cols 0-63); kt 2 (xs, cols 64-95) is register-resident.
__device__ __forceinline__ void loadA2(const char* G, int L, short8* Ah, short8* Al) {
#pragma unroll
    for (int kt = 0; kt < 2; ++kt) {
        Ah[kt] = *(const short8*)(G + (L & 15) * HSTR + kt * 64 + (L >> 4) * 16);
        Al[kt] = *(const short8*)(G + HLO + (L & 15) * HSTR + kt * 64 + (L >> 4) * 16);
    }
}
// One 4-N-tile GEMM pass: S[row][col 0..63] = A(16xK) @ B(Kx64).
template<int KT, int NT>
__device__ __forceinline__ void lin_pass(const u16* __restrict__ ws, int off, int nt0,
                                         const short8* Ah, const short8* Al,
                                         char* Sg, int L) {
#pragma unroll
    for (int ntc = 0; ntc < 4; ++ntc) {
        f32x4 a1 = {0.f, 0.f, 0.f, 0.f}, a2 = {0.f, 0.f, 0.f, 0.f};
#pragma unroll
        for (int kt = 0; kt < KT; ++kt) {
            int f = kt * NT + nt0 + ntc;
            short8 bh = *(const short8*)(ws + off + f * 1024 + L * 8);
            short8 bl = *(const short8*)(ws + off + f * 1024 + 512 + L * 8);
            a1 = mfma1(Ah[kt], bh, a1);
            a2 = mfma1(Ah[kt], bl, a2);
            a2 = mfma1(Al[kt], bh, a2);
        }
#pragma unroll
        for (int rr = 0; rr < 4; ++rr)   // C: row=(L>>4)*4+rr, col=ntc*16+(L&15)
            *(float*)(Sg + ((L >> 4) * 4 + rr) * SSTR + ntc * 64 + (L & 15) * 4) = a1[rr] + a2[rr];
    }
}
__device__ __forceinline__ void readS14(const char* Sg, int L, float* o) {
#pragma unroll
    for (int k = 0; k < 14; ++k) o[k] = *(const float*)(Sg + ROW(k) * SSTR + L * 4);
}
// stage 16 edge rows (chunk c of 6; 84 real edges) as PACKED u32 per element
__device__ __forceinline__ void stageH2(char* G, int c, const float* pp, const float* qq, int L) {
#pragma unroll
    for (int r = 0; r < 16; ++r) {
        int e = c * 16 + r;
        if (e < 84) {
            int gb = (e >= 42) ? 1 : 0;
            int el = e - gb * 42;
            int i = el / 6, jj = el - i * 6;
            int j = jj + (jj >= i);
            float hv = fmaxf(pp[gb * 7 + i] + qq[gb * 7 + j], 0.f);
            *(u32*)(G + r * H2S + L * 4) = splitpack(hv);
        }
    }
}
// de-interleave 4 packed u32 -> hi short8-half (2 u32) and lo half
__device__ __forceinline__ void unpack4(const uint4& a, u32* ho, u32* lo) {
    ho[0] = __builtin_amdgcn_perm(a.y, a.x, 0x05040100);
    ho[1] = __builtin_amdgcn_perm(a.w, a.z, 0x05040100);
    lo[0] = __builtin_amdgcn_perm(a.y, a.x, 0x07060302);
    lo[1] = __builtin_amdgcn_perm(a.w, a.z, 0x07060302);
}
__device__ __forceinline__ void loadAH(const char* G, int L,
                                       short8& Ah0, short8& Ah1, short8& Al0, short8& Al1) {
    const char* base = G + (L & 15) * H2S + (L >> 4) * 32;
    uint4 a0 = *(const uint4*)(base);
    uint4 a1 = *(const uint4*)(base + 16);
    uint4 b0 = *(const uint4*)(base + 128);
    uint4 b1 = *(const uint4*)(base + 144);
    union { u32 u[4]; short8 s; } h0, h1, l0, l1;
    unpack4(a0, &h0.u[0], &l0.u[0]);
    unpack4(a1, &h0.u[2], &l0.u[2]);
    unpack4(b0, &h1.u[0], &l1.u[0]);
    unpack4(b1, &h1.u[2], &l1.u[2]);
    Ah0 = h0.s; Al0 = l0.s; Ah1 = h1.s; Al1 = l1.s;
}
// fold chunk cc's S rows into per-node running max (column L)
__device__ __forceinline__ void maxread(const char* Sb, int cc, float* mx, int L) {
#pragma unroll
    for (int r = 0; r < 16; ++r) {
        int e = cc * 16 + r;
        if (e < 84) {
            int gb = (e >= 42) ? 1 : 0;
            int i = (e - gb * 42) / 6;
            float sv = *(const float*)(Sb + r * SSTR + L * 4);
            mx[gb * 7 + i] = fmaxf(mx[gb * 7 + i], sv);
        }
    }
}

// EdgeConv second linear (64->64) + max-agg + bias + relu via MFMA.
// Single-buffered H in W (chunk-c frags consumed into regs before restage).
// B-frags NOT resident (R16): reloaded per (chunk,nt) from ws — 16KB region
// re-read 6x stays L1-resident; frees 64 VGPRs for occupancy.
__device__ __forceinline__ void edgeconv_pipe(const u16* __restrict__ ws, int offB,
                                              char* W, char* Sb,
                                              const float* pp, const float* qq,
                                              float vb, int L) {
    float mx[14];
#pragma unroll
    for (int k = 0; k < 14; ++k) mx[k] = -3.0e38f;
    stageH2(W, 0, pp, qq, L);
    short8 Ah0, Ah1, Al0, Al1;
    loadAH(W, L, Ah0, Ah1, Al0, Al1);
#pragma unroll
    for (int c = 0; c < 6; ++c) {
        if (c < 5) stageH2(W, c + 1, pp, qq, L);   // frags for chunk c already in regs
        if (c > 0) maxread(Sb, c - 1, mx, L);      // before S is overwritten
#pragma unroll
        for (int nt = 0; nt < 4; ++nt) {
            short8 bh0 = *(const short8*)(ws + offB + nt * 1024 + L * 8);
            short8 bl0 = *(const short8*)(ws + offB + nt * 1024 + 512 + L * 8);
            short8 bh1 = *(const short8*)(ws + offB + (4 + nt) * 1024 + L * 8);
            short8 bl1 = *(const short8*)(ws + offB + (4 + nt) * 1024 + 512 + L * 8);
            f32x4 a1 = {0.f, 0.f, 0.f, 0.f}, a2 = {0.f, 0.f, 0.f, 0.f};
            a1 = mfma1(Ah0, bh0, a1);
            a2 = mfma1(Ah0, bl0, a2);
            a2 = mfma1(Al0, bh0, a2);
            a1 = mfma1(Ah1, bh1, a1);
            a2 = mfma1(Ah1, bl1, a2);
            a2 = mfma1(Al1, bh1, a2);
#pragma unroll
            for (int rr = 0; rr < 4; ++rr)
                *(float*)(Sb + ((L >> 4) * 4 + rr) * SSTR + nt * 64 + (L & 15) * 4) = a1[rr] + a2[rr];
        }
        if (c < 5) loadAH(W, L, Ah0, Ah1, Al0, Al1);   // reads chunk c+1 (DS in-order)
    }
    maxread(Sb, 5, mx, L);
    float xo[14];
#pragma unroll
    for (int k = 0; k < 14; ++k) xo[k] = fmaxf(mx[k] + vb, 0.f);
    writeX64_14(W, L, xo);
}

__global__ __launch_bounds__(128, 3) void gnn_kernel(
    const float* __restrict__ omega, const float* __restrict__ tt, const float* __restrict__ Wf,
    const float* __restrict__ wi1, const float* __restrict__ bi1, const float* __restrict__ bi2,
    const float* __restrict__ bt,
    const float* __restrict__ b1a, const float* __restrict__ b1b,
    const float* __restrict__ b2a, const float* __restrict__ b2b,
    const float* __restrict__ b3a, const float* __restrict__ b3b,
    const u16* __restrict__ ws, float* __restrict__ out)
{
    __shared__ __align__(16) char smem[2 * WREG];   // 17664 B/block
    const int L   = threadIdx.x & 63;
    const int wav = threadIdx.x >> 6;
    const int p   = blockIdx.x * 2 + wav;    // graph pair id, grid covers 25000
    const int g0  = p * 2;
    const int base0 = g0 * 7;                // g1 nodes start at base0+7
    char* W   = smem + wav * WREG;
    char* Sb  = W + 4608;

    // ---- h1 = relu(omega@wi1 + bi1), both graphs (42 contiguous coords) ----
    float omv = (L < 42) ? omega[base0 * 3 + L] : 0.f;
    float vwi10 = wi1[L], vwi11 = wi1[64 + L], vwi12 = wi1[128 + L];
    float vbi1 = bi1[L];
    float h1[14];
#pragma unroll
    for (int k = 0; k < 14; ++k) {
        float a0 = bcast(omv, 3 * k), a1 = bcast(omv, 3 * k + 1), a2 = bcast(omv, 3 * k + 2);
        h1[k] = fmaxf(fmaf(a0, vwi10, fmaf(a1, vwi11, fmaf(a2, vwi12, vbi1))), 0.f);
    }

    // ---- time embedding via MFMA (tile-bug: node n uses t[n % B]) ----
    // E staged in W (bf16 planes, cols 0-31); C -> Sb; xs staged back through W
    // once, then its A-frags (kt=2, constant all kernel) held in registers.
    short8 Ah2, Al2;
    {
        int cc = L & 31;
        float vwf = Wf[cc & 15] * 6.283185307179586f;
        int tb = base0 - (base0 / NB) * NB;        // base0 % NB
#pragma unroll
        for (int k = 0; k < 14; ++k) {
            int ti = tb + k; if (ti >= NB) ti -= NB;
            float pj = tt[ti] * vwf;
            float remb = fmaxf((cc < 16) ? __sinf(pj) : __cosf(pj), 0.f);
            u16 h, l;
            split2(remb, h, l);
            if (L < 32) *(u16*)(W + ROW(k) * HSTR + cc * 2) = h;
            else *(u16*)(W + HLO + ROW(k) * HSTR + cc * 2) = l;
        }
        short8 Eh = *(const short8*)(W + (L & 15) * HSTR + (L >> 4) * 16);
        short8 El = *(const short8*)(W + HLO + (L & 15) * HSTR + (L >> 4) * 16);
#pragma unroll
        for (int nt = 0; nt < 2; ++nt) {
            short8 bh = *(const short8*)(ws + OFF_WT + nt * 1024 + L * 8);
            short8 bl = *(const short8*)(ws + OFF_WT + nt * 1024 + 512 + L * 8);
            f32x4 acc = {0.f, 0.f, 0.f, 0.f};
            acc = mfma3(Eh, El, bh, bl, acc);
#pragma unroll
            for (int rr = 0; rr < 4; ++rr)
                *(float*)(Sb + ((L >> 4) * 4 + rr) * SSTR + nt * 64 + (L & 15) * 4) = acc[rr];
        }
        float vbt = bt[cc];
#pragma unroll
        for (int k = 0; k < 14; ++k) {
            float xv = fmaxf(*(const float*)(Sb + ROW(k) * SSTR + cc * 4) + vbt, 0.f);
            u16 h, l;
            split2(xv, h, l);
            if (L < 32) *(u16*)(W + ROW(k) * HSTR + cc * 2) = h;
            else *(u16*)(W + HLO + ROW(k) * HSTR + cc * 2) = l;
        }
        // xs A-frag (cols 0-31 of W == k 64..95), resident for L2a/L3a
        Ah2 = *(const short8*)(W + (L & 15) * HSTR + (L >> 4) * 16);
        Al2 = *(const short8*)(W + HLO + (L & 15) * HSTR + (L >> 4) * 16);
    }

    short8 Ah[3], Al[3];
    float pp[14], qq[14];

    // ---- init: x0 = h1 @ wi2 + bi2  (X: W, S: Sb, X back to W) ----
    writeX64_14(W, L, h1);
    loadA2(W, L, Ah, Al);
    lin_pass<2, 4>(ws, OFF_I, 0, Ah, Al, Sb, L);
    {
        float xh[14];
        readS14(Sb, L, xh);
        float vbi2 = bi2[L];
#pragma unroll
        for (int k = 0; k < 14; ++k) xh[k] += vbi2;
        writeX64_14(W, L, xh);
    }

    // ---- L1a (K=64): A from W, S in Sb ----
    loadA2(W, L, Ah, Al);
    lin_pass<2, 8>(ws, OFF_1A, 0, Ah, Al, Sb, L);
    readS14(Sb, L, pp);
    lin_pass<2, 8>(ws, OFF_1A, 4, Ah, Al, Sb, L);
    readS14(Sb, L, qq);
    float vb1a = b1a[L];
#pragma unroll
    for (int k = 0; k < 14; ++k) pp[k] = pp[k] + vb1a - qq[k];
    // ---- L1b (X out -> W) ----
    edgeconv_pipe(ws, OFF_1B, W, Sb, pp, qq, b1b[L], L);

    // ---- L2a (K=96: [x | xs]) ----
    loadA2(W, L, Ah, Al);
    Ah[2] = Ah2; Al[2] = Al2;
    lin_pass<3, 8>(ws, OFF_2A, 0, Ah, Al, Sb, L);
    readS14(Sb, L, pp);
    lin_pass<3, 8>(ws, OFF_2A, 4, Ah, Al, Sb, L);
    readS14(Sb, L, qq);
    float vb2a = b2a[L];
#pragma unroll
    for (int k = 0; k < 14; ++k) pp[k] = pp[k] + vb2a - qq[k];
    // ---- L2b ----
    edgeconv_pipe(ws, OFF_2B, W, Sb, pp, qq, b2b[L], L);

    // ---- L3a (K=96) ----
    loadA2(W, L, Ah, Al);
    Ah[2] = Ah2; Al[2] = Al2;
    lin_pass<3, 8>(ws, OFF_3A, 0, Ah, Al, Sb, L);
    readS14(Sb, L, pp);
    lin_pass<3, 8>(ws, OFF_3A, 4, Ah, Al, Sb, L);
    readS14(Sb, L, qq);
    float vb3a = b3a[L];
#pragma unroll
    for (int k = 0; k < 14; ++k) pp[k] = pp[k] + vb3a - qq[k];

    // ---- L3b (64->3) via MFMA (single-buffered) + max + /(std+1e-7) ----
    {
        short8 B0h = *(const short8*)(ws + OFF_3B + L * 8);
        short8 B0l = *(const short8*)(ws + OFF_3B + 512 + L * 8);
        short8 B1h = *(const short8*)(ws + OFF_3B + 1024 + L * 8);
        short8 B1l = *(const short8*)(ws + OFF_3B + 1536 + L * 8);
        stageH2(W, 0, pp, qq, L);
        short8 Ah0, Ah1, Al0, Al1;
        loadAH(W, L, Ah0, Ah1, Al0, Al1);
#pragma unroll
        for (int c = 0; c < 6; ++c) {
            if (c < 5) stageH2(W, c + 1, pp, qq, L);
            f32x4 a1 = {0.f, 0.f, 0.f, 0.f}, a2 = {0.f, 0.f, 0.f, 0.f};
            a1 = mfma1(Ah0, B0h, a1);
            a2 = mfma1(Ah0, B0l, a2);
            a2 = mfma1(Al0, B0h, a2);
            a1 = mfma1(Ah1, B1h, a1);
            a2 = mfma1(Ah1, B1l, a2);
            a2 = mfma1(Al1, B1h, a2);
            if ((L & 15) < 3) {       // compact strip: row e (96), stride 16B, col 0..2
#pragma unroll
                for (int rr = 0; rr < 4; ++rr)
                    *(float*)(Sb + (c * 16 + (L >> 4) * 4 + rr) * 16 + (L & 15) * 4) = a1[rr] + a2[rr];
            }
            if (c < 5) loadAH(W, L, Ah0, Ah1, Al0, Al1);
        }
        if (L < 42) {                 // lanes 0-20: g0; 21-41: g1
            int gb = (L >= 21) ? 1 : 0;
            int ll = L - gb * 21;
            int i = ll / 3, col = ll - i * 3;
            int e0 = gb * 42 + i * 6;
            float m = -3.0e38f;
#pragma unroll
            for (int e6 = 0; e6 < 6; ++e6)
                m = fmaxf(m, *(const float*)(Sb + (e0 + e6) * 16 + col * 4));
            m += b3b[col];
            float tg = tt[g0 + gb];   // std uses t[n // 7]
            float stdv = sqrtf((exp2f(tg * 9.287712379549448f) - 1.0f) * 0.15533740282828987f);
            out[base0 * 3 + L] = m / (stdv + 1e-7f);   // contiguous 42 outputs
        }
    }
}

extern "C" void kernel_launch(void* const* d_in, const int* in_sizes, int n_in,
                              void* d_out, int out_size, void* d_ws, size_t ws_size,
                              hipStream_t stream) {
    const float* omega = (const float*)d_in[0];
    // d_in[1] edge_index unused (fixed fully-connected); d_in[3] num_objs == 7
    const float* tt  = (const float*)d_in[2];
    const float* Wf  = (const float*)d_in[4];
    const float* wi1 = (const float*)d_in[5];
    const float* bi1 = (const float*)d_in[6];
    const float* wi2 = (const float*)d_in[7];
    const float* bi2 = (const float*)d_in[8];
    const float* wt  = (const float*)d_in[9];
    const float* bt  = (const float*)d_in[10];
    const float* w1a = (const float*)d_in[11];
    const float* b1a = (const float*)d_in[12];
    const float* w1b = (const float*)d_in[13];
    const float* b1b = (const float*)d_in[14];
    const float* w2a = (const float*)d_in[15];
    const float* b2a = (const float*)d_in[16];
    const float* w2b = (const float*)d_in[17];
    const float* b2b = (const float*)d_in[18];
    const float* w3a = (const float*)d_in[19];
    const float* b3a = (const float*)d_in[20];
    const float* w3b = (const float*)d_in[21];
    const float* b3b = (const float*)d_in[22];
    u16* ws = (u16*)d_ws;   // needs 188416 bytes

    pack_kernel<<<dim3(92, 8), dim3(128), 0, stream>>>(wi2, w1a, w2a, w3a, w1b, w2b, wt, w3b, ws);
    gnn_kernel<<<dim3(12500), dim3(128), 0, stream>>>(
        omega, tt, Wf, wi1, bi1, bi2, bt,
        b1a, b1b, b2a, b2b, b3a, b3b, ws, (float*)d_out);
}

// Round 4
// 400.073 us; speedup vs baseline: 1.7024x; 1.0384x over previous
//
#include <hip/hip_runtime.h>

// ScoreNetGNN: B=50000 graphs x 7 nodes, fully-connected (42 edges/graph).
// R6: MFMA pipeline (16x16x32 bf16 split hi+lo). R12: truncation-split.
// R13: parallel pack + packed-H. R14: LDS 8832/wave; (128,4) over-pin -> spill.
// R15: natural alloc -> 2 waves/SIMD (total regs>170). R16: B-frags reloaded
//   from L1 per use + (128,3): occ 22->31.4%, 343us counters; small spill
//   (WRITE 34MB) shows pressure ~170.
// R17 (this): kill the H staging pipeline.
//   pp/qq written ONCE per edgeconv to a transposed PQ LDS region (28 rows x
//   288B; rows 0-15 overlay the dead X region). Each lane builds its MFMA
//   A-frag DIRECTLY from 8-feature slices of PQ: b128 reads + add/relu +
//   hi-perm + v_cvt_pk_bf16_f32 lo. Deletes stageH2/loadAH/unpack4
//   (~1700 VALU/wave, -18%), frees pp/qq's 28 regs (spill should vanish).
//   LDS/wave 8832->12288 -> 6 blocks/CU = 12-wave cap (= reg cap, neutral).
// f32 I/O hardcoded (R3 counters: WRITE_SIZE = 4 B/elem).

#define NB 50000

typedef unsigned short u16;
typedef unsigned int u32;
typedef short short8 __attribute__((ext_vector_type(8)));
typedef float f32x4 __attribute__((ext_vector_type(4)));

// d_ws fragment offsets (u16 units). frag stride 1024 u16 (hi 512 | lo 512),
// lane entry = 8 u16 (16B). Total 94208 u16 = 188416 bytes.
#define OFF_I  0
#define OFF_1A 8192
#define OFF_2A 24576
#define OFF_3A 49152
#define OFF_1B 73728
#define OFF_2B 81920
#define OFF_WT 90112
#define OFF_3B 92160

// LDS per-wave geometry (bytes), base W:
//  [0,4608)    X: 16 rows x 64 bf16 @ stride 144, hi [0,2304) lo [2304,4608)
//              == PQ rows 0-15 during edgeconv (X dead then)
//  [4608,8064) PQ rows 16-27 (PQ: 28 rows x 64 f32 @ stride 288;
//              rows 0-13 = pp[node], rows 14-27 = qq[node])
//  [8064,12288) Sb: f32 C 16 rows @ stride 264
#define HSTR 144
#define HLO  2304
#define PQS  288
#define SOFF 8064
#define SSTR 264
#define WREG 12288

__device__ __forceinline__ float b2f(u16 u) {
    return __uint_as_float(((u32)u) << 16);
}
__device__ __forceinline__ u16 f2b(float f) {
    u32 u = __float_as_uint(f);
    u += 0x7FFFu + ((u >> 16) & 1u);   // RNE
    return (u16)(u >> 16);
}
// split v into bf16 hi (truncated, v-hi exact) + bf16 lo (RNE of residual)
__device__ __forceinline__ void split2(float v, u16& h, u16& l) {
    u32 u = __float_as_uint(v);
    h = (u16)(u >> 16);
    float d = v - __uint_as_float(u & 0xffff0000u);
    l = f2b(d);
}
__device__ __forceinline__ float bcast(float v, int l) {
    return __uint_as_float(__builtin_amdgcn_readlane(__float_as_uint(v), l));
}

// ---- setup: pack weights into split-bf16 MFMA B-fragments ----
// grid (92, 8): blockIdx.y = element j within lane entry; 128 thr = half x lane.
__global__ __launch_bounds__(128) void pack_kernel(
    const float* __restrict__ wi2, const float* __restrict__ w1a,
    const float* __restrict__ w2a, const float* __restrict__ w3a,
    const float* __restrict__ w1b, const float* __restrict__ w2b,
    const float* __restrict__ wt,  const float* __restrict__ w3b,
    u16* __restrict__ ws)
{
    int blk = blockIdx.x;
    int j    = blockIdx.y;
    int half = threadIdx.x >> 6;          // 0 = hi, 1 = lo
    int lane = threadIdx.x & 63;
    float v;
    u16* dst;
    if (blk < 88) {
        const float* src; int NT, qoff, obase, frag;
        if (blk < 8)       { src = wi2; NT = 4; qoff = 0;  obase = OFF_I;  frag = blk;      }
        else if (blk < 24) { src = w1a; NT = 8; qoff = 64; obase = OFF_1A; frag = blk - 8;  }
        else if (blk < 48) { src = w2a; NT = 8; qoff = 96; obase = OFF_2A; frag = blk - 24; }
        else if (blk < 72) { src = w3a; NT = 8; qoff = 96; obase = OFF_3A; frag = blk - 48; }
        else if (blk < 80) { src = w1b; NT = 4; qoff = 0;  obase = OFF_1B; frag = blk - 72; }
        else               { src = w2b; NT = 4; qoff = 0;  obase = OFF_2B; frag = blk - 80; }
        int kt = frag / NT, nt = frag % NT;
        int k = kt * 32 + (lane >> 4) * 8 + j;
        int n = nt * 16 + (lane & 15);
        int idx = (n < 64) ? (k * 64 + n) : ((qoff + k) * 64 + (n - 64));
        v = src[idx];
        dst = ws + obase + frag * 1024 + half * 512 + lane * 8 + j;
    } else if (blk < 90) {               // wt (32,32): 2 n-frags
        int frag = blk - 88;
        int k = (lane >> 4) * 8 + j;
        int n = frag * 16 + (lane & 15);
        v = wt[k * 32 + n];
        dst = ws + OFF_WT + frag * 1024 + half * 512 + lane * 8 + j;
    } else {                             // w3b (64,3): 2 k-frags, cols 3..15 = 0
        int frag = blk - 90;
        int k = frag * 32 + (lane >> 4) * 8 + j;
        int n = lane & 15;
        v = (n < 3) ? w3b[k * 3 + n] : 0.f;
        dst = ws + OFF_3B + frag * 1024 + half * 512 + lane * 8 + j;
    }
    u16 hi = f2b(v);
    *dst = (half == 0) ? hi : f2b(v - b2f(hi));
}

__device__ __forceinline__ f32x4 mfma1(short8 a, short8 b, f32x4 acc) {
    return __builtin_amdgcn_mfma_f32_16x16x32_bf16(a, b, acc, 0, 0, 0);
}
__device__ __forceinline__ f32x4 mfma3(short8 ah, short8 al, short8 bh, short8 bl, f32x4 acc) {
    acc = mfma1(ah, bh, acc);
    acc = mfma1(ah, bl, acc);
    acc = mfma1(al, bh, acc);
    return acc;   // lo*lo dropped
}

// node k (0..13) -> row (g0 rows 0-6, g1 rows 8-14; rows 7,15 stale/unread)
#define ROW(k) ((k) < 7 ? (k) : (k) + 1)

// write 14 node values (64 cols) into region G as X (bf16 hi/lo planes)
__device__ __forceinline__ void writeX64_14(char* G, int L, const float* v) {
#pragma unroll
    for (int k = 0; k < 14; ++k) {
        int r = ROW(k);
        u16 h, l;
        split2(v[k], h, l);
        *(u16*)(G + r * HSTR + L * 2) = h;
        *(u16*)(G + HLO + r * HSTR + L * 2) = l;
    }
}
// A-frags kt 0,1 from G (cols 0-63); kt 2 (xs) is register-resident.
__device__ __forceinline__ void loadA2(const char* G, int L, short8* Ah, short8* Al) {
#pragma unroll
    for (int kt = 0; kt < 2; ++kt) {
        Ah[kt] = *(const short8*)(G + (L & 15) * HSTR + kt * 64 + (L >> 4) * 16);
        Al[kt] = *(const short8*)(G + HLO + (L & 15) * HSTR + kt * 64 + (L >> 4) * 16);
    }
}
// One 4-N-tile GEMM pass: S[row][col 0..63] = A(16xK) @ B(Kx64).
template<int KT, int NT>
__device__ __forceinline__ void lin_pass(const u16* __restrict__ ws, int off, int nt0,
                                         const short8* Ah, const short8* Al,
                                         char* Sg, int L) {
#pragma unroll
    for (int ntc = 0; ntc < 4; ++ntc) {
        f32x4 a1 = {0.f, 0.f, 0.f, 0.f}, a2 = {0.f, 0.f, 0.f, 0.f};
#pragma unroll
        for (int kt = 0; kt < KT; ++kt) {
            int f = kt * NT + nt0 + ntc;
            short8 bh = *(const short8*)(ws + off + f * 1024 + L * 8);
            short8 bl = *(const short8*)(ws + off + f * 1024 + 512 + L * 8);
            a1 = mfma1(Ah[kt], bh, a1);
            a2 = mfma1(Ah[kt], bl, a2);
            a2 = mfma1(Al[kt], bh, a2);
        }
#pragma unroll
        for (int rr = 0; rr < 4; ++rr)   // C: row=(L>>4)*4+rr, col=ntc*16+(L&15)
            *(float*)(Sg + ((L >> 4) * 4 + rr) * SSTR + ntc * 64 + (L & 15) * 4) = a1[rr] + a2[rr];
    }
}
__device__ __forceinline__ void readS14(const char* Sg, int L, float* o) {
#pragma unroll
    for (int k = 0; k < 14; ++k) o[k] = *(const float*)(Sg + ROW(k) * SSTR + L * 4);
}
// write pp (rows 0-13) / qq (rows 14-27) transposed into PQ region
__device__ __forceinline__ void writePQ(char* PQ, int L, const float* pp, const float* qq) {
#pragma unroll
    for (int k = 0; k < 14; ++k) {
        *(float*)(PQ + k * PQS + L * 4) = pp[k];
        *(float*)(PQ + (14 + k) * PQS + L * 4) = qq[k];
    }
}
// build one 16x32 A-frag (hi+lo) for this lane from 8-feature PQ slices.
// bp/bq point at the lane's p-row / q-row + (L>>4)*32 + kt*128.
__device__ __forceinline__ void buildA1(const char* bp, const char* bq,
                                        short8& Ah, short8& Al) {
    f32x4 p0 = *(const f32x4*)bp,  p1 = *(const f32x4*)(bp + 16);
    f32x4 q0 = *(const f32x4*)bq,  q1 = *(const f32x4*)(bq + 16);
    float h[8];
#pragma unroll
    for (int x = 0; x < 4; ++x) h[x]     = fmaxf(p0[x] + q0[x], 0.f);
#pragma unroll
    for (int x = 0; x < 4; ++x) h[4 + x] = fmaxf(p1[x] + q1[x], 0.f);
    union { u32 u[4]; short8 s; } H, Lo;
#pragma unroll
    for (int x = 0; x < 4; ++x) {
        float a = h[2 * x], b = h[2 * x + 1];
        u32 ua = __float_as_uint(a), ub = __float_as_uint(b);
        H.u[x] = __builtin_amdgcn_perm(ub, ua, 0x07060302);   // [hi(a) | hi(b)]
        float da = a - __uint_as_float(ua & 0xffff0000u);
        float db = b - __uint_as_float(ub & 0xffff0000u);
        u32 r;
        asm("v_cvt_pk_bf16_f32 %0, %1, %2" : "=v"(r) : "v"(da), "v"(db));
        Lo.u[x] = r;                                           // [lo(a) | lo(b)]
    }
    Ah = H.s; Al = Lo.s;
}
// build both K-halves (features 0-31, 32-63) of chunk c's A-tile for this lane
__device__ __forceinline__ void buildA(const char* PQ, int c, int L,
                                       short8& Ah0, short8& Al0,
                                       short8& Ah1, short8& Al1) {
    int e  = c * 16 + (L & 15);
    int gb = (e >= 42) ? 1 : 0;
    int el = e - gb * 42;               // rows with e>=84 give i=7,8 -> reads
    int i  = el / 6;                    // land in qq rows 14,15 (in-bounds
    int jj = el - i * 6;                // garbage; outputs discarded)
    int j  = jj + (jj >= i);
    const char* bp = PQ + (gb * 7 + i) * PQS + (L >> 4) * 32;
    const char* bq = PQ + (14 + gb * 7 + j) * PQS + (L >> 4) * 32;
    buildA1(bp,       bq,       Ah0, Al0);
    buildA1(bp + 128, bq + 128, Ah1, Al1);
}
// fold chunk cc's S rows into per-node running max (column L)
__device__ __forceinline__ void maxread(const char* Sb, int cc, float* mx, int L) {
#pragma unroll
    for (int r = 0; r < 16; ++r) {
        int e = cc * 16 + r;
        if (e < 84) {
            int gb = (e >= 42) ? 1 : 0;
            int i = (e - gb * 42) / 6;
            float sv = *(const float*)(Sb + r * SSTR + L * 4);
            mx[gb * 7 + i] = fmaxf(mx[gb * 7 + i], sv);
        }
    }
}

// EdgeConv second linear (64->64) + max-agg + bias + relu via MFMA.
// A-frags built per chunk directly from PQ (no H staging). B-frags reloaded
// per (chunk,nt) from ws (L1-resident). Output X written into W.
__device__ __forceinline__ void edgeconv_pipe(const u16* __restrict__ ws, int offB,
                                              char* W, char* Sb, float vb, int L) {
    const char* PQ = W;
    float mx[14];
#pragma unroll
    for (int k = 0; k < 14; ++k) mx[k] = -3.0e38f;
    short8 Ah0, Ah1, Al0, Al1;
    buildA(PQ, 0, L, Ah0, Al0, Ah1, Al1);
#pragma unroll
    for (int c = 0; c < 6; ++c) {
        if (c > 0) maxread(Sb, c - 1, mx, L);      // before S is overwritten
#pragma unroll
        for (int nt = 0; nt < 4; ++nt) {
            short8 bh0 = *(const short8*)(ws + offB + nt * 1024 + L * 8);
            short8 bl0 = *(const short8*)(ws + offB + nt * 1024 + 512 + L * 8);
            short8 bh1 = *(const short8*)(ws + offB + (4 + nt) * 1024 + L * 8);
            short8 bl1 = *(const short8*)(ws + offB + (4 + nt) * 1024 + 512 + L * 8);
            f32x4 a1 = {0.f, 0.f, 0.f, 0.f}, a2 = {0.f, 0.f, 0.f, 0.f};
            a1 = mfma1(Ah0, bh0, a1);
            a2 = mfma1(Ah0, bl0, a2);
            a2 = mfma1(Al0, bh0, a2);
            a1 = mfma1(Ah1, bh1, a1);
            a2 = mfma1(Ah1, bl1, a2);
            a2 = mfma1(Al1, bh1, a2);
#pragma unroll
            for (int rr = 0; rr < 4; ++rr)
                *(float*)(Sb + ((L >> 4) * 4 + rr) * SSTR + nt * 64 + (L & 15) * 4) = a1[rr] + a2[rr];
        }
        if (c < 5) buildA(PQ, c + 1, L, Ah0, Al0, Ah1, Al1);
    }
    maxread(Sb, 5, mx, L);
    float xo[14];
#pragma unroll
    for (int k = 0; k < 14; ++k) xo[k] = fmaxf(mx[k] + vb, 0.f);
    writeX64_14(W, L, xo);       // overwrites PQ rows 0-15 (dead)
}

__global__ __launch_bounds__(128, 3) void gnn_kernel(
    const float* __restrict__ omega, const float* __restrict__ tt, const float* __restrict__ Wf,
    const float* __restrict__ wi1, const float* __restrict__ bi1, const float* __restrict__ bi2,
    const float* __restrict__ bt,
    const float* __restrict__ b1a, const float* __restrict__ b1b,
    const float* __restrict__ b2a, const float* __restrict__ b2b,
    const float* __restrict__ b3a, const float* __restrict__ b3b,
    const u16* __restrict__ ws, float* __restrict__ out)
{
    __shared__ __align__(16) char smem[2 * WREG];   // 24576 B/block
    const int L   = threadIdx.x & 63;
    const int wav = threadIdx.x >> 6;
    const int p   = blockIdx.x * 2 + wav;    // graph pair id, grid covers 25000
    const int g0  = p * 2;
    const int base0 = g0 * 7;                // g1 nodes start at base0+7
    char* W   = smem + wav * WREG;
    char* Sb  = W + SOFF;

    // ---- h1 = relu(omega@wi1 + bi1), both graphs (42 contiguous coords) ----
    float omv = (L < 42) ? omega[base0 * 3 + L] : 0.f;
    float vwi10 = wi1[L], vwi11 = wi1[64 + L], vwi12 = wi1[128 + L];
    float vbi1 = bi1[L];
    float h1[14];
#pragma unroll
    for (int k = 0; k < 14; ++k) {
        float a0 = bcast(omv, 3 * k), a1 = bcast(omv, 3 * k + 1), a2 = bcast(omv, 3 * k + 2);
        h1[k] = fmaxf(fmaf(a0, vwi10, fmaf(a1, vwi11, fmaf(a2, vwi12, vbi1))), 0.f);
    }

    // ---- time embedding via MFMA (tile-bug: node n uses t[n % B]) ----
    // E staged in W (bf16 planes, cols 0-31); C -> Sb; xs staged back through W
    // once, then its A-frags (kt=2, constant all kernel) held in registers.
    short8 Ah2, Al2;
    {
        int cc = L & 31;
        float vwf = Wf[cc & 15] * 6.283185307179586f;
        int tb = base0 - (base0 / NB) * NB;        // base0 % NB
#pragma unroll
        for (int k = 0; k < 14; ++k) {
            int ti = tb + k; if (ti >= NB) ti -= NB;
            float pj = tt[ti] * vwf;
            float remb = fmaxf((cc < 16) ? __sinf(pj) : __cosf(pj), 0.f);
            u16 h, l;
            split2(remb, h, l);
            if (L < 32) *(u16*)(W + ROW(k) * HSTR + cc * 2) = h;
            else *(u16*)(W + HLO + ROW(k) * HSTR + cc * 2) = l;
        }
        short8 Eh = *(const short8*)(W + (L & 15) * HSTR + (L >> 4) * 16);
        short8 El = *(const short8*)(W + HLO + (L & 15) * HSTR + (L >> 4) * 16);
#pragma unroll
        for (int nt = 0; nt < 2; ++nt) {
            short8 bh = *(const short8*)(ws + OFF_WT + nt * 1024 + L * 8);
            short8 bl = *(const short8*)(ws + OFF_WT + nt * 1024 + 512 + L * 8);
            f32x4 acc = {0.f, 0.f, 0.f, 0.f};
            acc = mfma3(Eh, El, bh, bl, acc);
#pragma unroll
            for (int rr = 0; rr < 4; ++rr)
                *(float*)(Sb + ((L >> 4) * 4 + rr) * SSTR + nt * 64 + (L & 15) * 4) = acc[rr];
        }
        float vbt = bt[cc];
#pragma unroll
        for (int k = 0; k < 14; ++k) {
            float xv = fmaxf(*(const float*)(Sb + ROW(k) * SSTR + cc * 4) + vbt, 0.f);
            u16 h, l;
            split2(xv, h, l);
            if (L < 32) *(u16*)(W + ROW(k) * HSTR + cc * 2) = h;
            else *(u16*)(W + HLO + ROW(k) * HSTR + cc * 2) = l;
        }
        // xs A-frag (cols 0-31 of W == k 64..95), resident for L2a/L3a
        Ah2 = *(const short8*)(W + (L & 15) * HSTR + (L >> 4) * 16);
        Al2 = *(const short8*)(W + HLO + (L & 15) * HSTR + (L >> 4) * 16);
    }

    short8 Ah[3], Al[3];

    // ---- init: x0 = h1 @ wi2 + bi2  (X: W, S: Sb, X back to W) ----
    writeX64_14(W, L, h1);
    loadA2(W, L, Ah, Al);
    lin_pass<2, 4>(ws, OFF_I, 0, Ah, Al, Sb, L);
    {
        float xh[14];
        readS14(Sb, L, xh);
        float vbi2 = bi2[L];
#pragma unroll
        for (int k = 0; k < 14; ++k) xh[k] += vbi2;
        writeX64_14(W, L, xh);
    }

    // ---- L1a (K=64): A from W, S in Sb ----
    {
        float pp[14], qq[14];
        loadA2(W, L, Ah, Al);
        lin_pass<2, 8>(ws, OFF_1A, 0, Ah, Al, Sb, L);
        readS14(Sb, L, pp);
        lin_pass<2, 8>(ws, OFF_1A, 4, Ah, Al, Sb, L);
        readS14(Sb, L, qq);
        float vb = b1a[L];
#pragma unroll
        for (int k = 0; k < 14; ++k) pp[k] = pp[k] + vb - qq[k];
        writePQ(W, L, pp, qq);     // X in W already consumed by loadA2
    }
    // ---- L1b (X out -> W) ----
    edgeconv_pipe(ws, OFF_1B, W, Sb, b1b[L], L);

    // ---- L2a (K=96: [x | xs]) ----
    {
        float pp[14], qq[14];
        loadA2(W, L, Ah, Al);
        Ah[2] = Ah2; Al[2] = Al2;
        lin_pass<3, 8>(ws, OFF_2A, 0, Ah, Al, Sb, L);
        readS14(Sb, L, pp);
        lin_pass<3, 8>(ws, OFF_2A, 4, Ah, Al, Sb, L);
        readS14(Sb, L, qq);
        float vb = b2a[L];
#pragma unroll
        for (int k = 0; k < 14; ++k) pp[k] = pp[k] + vb - qq[k];
        writePQ(W, L, pp, qq);
    }
    // ---- L2b ----
    edgeconv_pipe(ws, OFF_2B, W, Sb, b2b[L], L);

    // ---- L3a (K=96) ----
    {
        float pp[14], qq[14];
        loadA2(W, L, Ah, Al);
        Ah[2] = Ah2; Al[2] = Al2;
        lin_pass<3, 8>(ws, OFF_3A, 0, Ah, Al, Sb, L);
        readS14(Sb, L, pp);
        lin_pass<3, 8>(ws, OFF_3A, 4, Ah, Al, Sb, L);
        readS14(Sb, L, qq);
        float vb = b3a[L];
#pragma unroll
        for (int k = 0; k < 14; ++k) pp[k] = pp[k] + vb - qq[k];
        writePQ(W, L, pp, qq);
    }

    // ---- L3b (64->3) via MFMA + max + /(std+1e-7) ----
    {
        const char* PQ = W;
        short8 B0h = *(const short8*)(ws + OFF_3B + L * 8);
        short8 B0l = *(const short8*)(ws + OFF_3B + 512 + L * 8);
        short8 B1h = *(const short8*)(ws + OFF_3B + 1024 + L * 8);
        short8 B1l = *(const short8*)(ws + OFF_3B + 1536 + L * 8);
        short8 Ah0, Ah1, Al0, Al1;
        buildA(PQ, 0, L, Ah0, Al0, Ah1, Al1);
#pragma unroll
        for (int c = 0; c < 6; ++c) {
            f32x4 a1 = {0.f, 0.f, 0.f, 0.f}, a2 = {0.f, 0.f, 0.f, 0.f};
            a1 = mfma1(Ah0, B0h, a1);
            a2 = mfma1(Ah0, B0l, a2);
            a2 = mfma1(Al0, B0h, a2);
            a1 = mfma1(Ah1, B1h, a1);
            a2 = mfma1(Ah1, B1l, a2);
            a2 = mfma1(Al1, B1h, a2);
            if ((L & 15) < 3) {       // compact strip: row e (96), stride 16B, col 0..2
#pragma unroll
                for (int rr = 0; rr < 4; ++rr)
                    *(float*)(Sb + (c * 16 + (L >> 4) * 4 + rr) * 16 + (L & 15) * 4) = a1[rr] + a2[rr];
            }
            if (c < 5) buildA(PQ, c + 1, L, Ah0, Al0, Ah1, Al1);
        }
        if (L < 42) {                 // lanes 0-20: g0; 21-41: g1
            int gb = (L >= 21) ? 1 : 0;
            int ll = L - gb * 21;
            int i = ll / 3, col = ll - i * 3;
            int e0 = gb * 42 + i * 6;
            float m = -3.0e38f;
#pragma unroll
            for (int e6 = 0; e6 < 6; ++e6)
                m = fmaxf(m, *(const float*)(Sb + (e0 + e6) * 16 + col * 4));
            m += b3b[col];
            float tg = tt[g0 + gb];   // std uses t[n // 7]
            float stdv = sqrtf((exp2f(tg * 9.287712379549448f) - 1.0f) * 0.15533740282828987f);
            out[base0 * 3 + L] = m / (stdv + 1e-7f);   // contiguous 42 outputs
        }
    }
}

extern "C" void kernel_launch(void* const* d_in, const int* in_sizes, int n_in,
                              void* d_out, int out_size, void* d_ws, size_t ws_size,
                              hipStream_t stream) {
    const float* omega = (const float*)d_in[0];
    // d_in[1] edge_index unused (fixed fully-connected); d_in[3] num_objs == 7
    const float* tt  = (const float*)d_in[2];
    const float* Wf  = (const float*)d_in[4];
    const float* wi1 = (const float*)d_in[5];
    const float* bi1 = (const float*)d_in[6];
    const float* wi2 = (const float*)d_in[7];
    const float* bi2 = (const float*)d_in[8];
    const float* wt  = (const float*)d_in[9];
    const float* bt  = (const float*)d_in[10];
    const float* w1a = (const float*)d_in[11];
    const float* b1a = (const float*)d_in[12];
    const float* w1b = (const float*)d_in[13];
    const float* b1b = (const float*)d_in[14];
    const float* w2a = (const float*)d_in[15];
    const float* b2a = (const float*)d_in[16];
    const float* w2b = (const float*)d_in[17];
    const float* b2b = (const float*)d_in[18];
    const float* w3a = (const float*)d_in[19];
    const float* b3a = (const float*)d_in[20];
    const float* w3b = (const float*)d_in[21];
    const float* b3b = (const float*)d_in[22];
    u16* ws = (u16*)d_ws;   // needs 188416 bytes

    pack_kernel<<<dim3(92, 8), dim3(128), 0, stream>>>(wi2, w1a, w2a, w3a, w1b, w2b, wt, w3b, ws);
    gnn_kernel<<<dim3(12500), dim3(128), 0, stream>>>(
        omega, tt, Wf, wi1, bi1, bi2, bt,
        b1a, b1b, b2a, b2b, b3a, b3b, ws, (float*)d_out);
}